// Round 3
// baseline (582.833 us; speedup 1.0000x reference)
//
#include <hip/hip_runtime.h>
#include <hip/hip_bf16.h>
#include <math.h>

#define B_   4
#define T_   2048
#define V_   512
#define D_   256
#define H_   4
#define DH_  64
#define NB_  32
#define DFF_ 1024
#define NL_  2

typedef __attribute__((ext_vector_type(8))) short short8_t;
typedef __attribute__((ext_vector_type(4))) float float4_t;

#define MFMA16(a,b,c) __builtin_amdgcn_mfma_f32_16x16x32_bf16(a,b,c,0,0,0)

__device__ __forceinline__ unsigned short f2bf_bits(float f) {
    unsigned u = __float_as_uint(f);
    u += 0x7fffu + ((u >> 16) & 1u);
    return (unsigned short)(u >> 16);
}

// ---------------------------------------------------------------------------
// Weight transpose+cast: W[K][N] fp32 -> Wt[N][K] bf16. One 32x32 tile/block.
// ---------------------------------------------------------------------------
__global__ __launch_bounds__(256) void wt_kernel(
    const float* __restrict__ Wq, const float* __restrict__ Wk,
    const float* __restrict__ Wv, const float* __restrict__ Wo,
    const float* __restrict__ W1, const float* __restrict__ W2,
    const float* __restrict__ Wout,
    unsigned short* __restrict__ wqt, unsigned short* __restrict__ wkt,
    unsigned short* __restrict__ wvt, unsigned short* __restrict__ wot,
    unsigned short* __restrict__ w1t, unsigned short* __restrict__ w2t,
    unsigned short* __restrict__ woutt)
{
    __shared__ float tile[32][33];
    int bx = blockIdx.x, tid = threadIdx.x;
    const float* src; unsigned short* dst; int Kd, Nd, tr, tc;
    if (bx < 512) {                    // Wq/Wk/Wv/Wo, 2 layers each, 256x256
        int am = bx >> 6, t = bx & 63;
        const float* s4[4] = {Wq, Wk, Wv, Wo};
        unsigned short* d4[4] = {wqt, wkt, wvt, wot};
        src = s4[am >> 1] + (long)(am & 1) * 65536;
        dst = d4[am >> 1] + (long)(am & 1) * 65536;
        Kd = 256; Nd = 256; tr = t >> 3; tc = t & 7;
    } else if (bx < 1024) {            // W1: 2 x (256x1024)
        int idx = bx - 512, mat = idx >> 8, t = idx & 255;
        src = W1 + (long)mat * 262144; dst = w1t + (long)mat * 262144;
        Kd = 256; Nd = 1024; tr = t >> 5; tc = t & 31;
    } else if (bx < 1536) {            // W2: 2 x (1024x256)
        int idx = bx - 1024, mat = idx >> 8, t = idx & 255;
        src = W2 + (long)mat * 262144; dst = w2t + (long)mat * 262144;
        Kd = 1024; Nd = 256; tr = t >> 3; tc = t & 7;
    } else {                           // Wout: 256x512
        int t = bx - 1536;
        src = Wout; dst = woutt; Kd = 256; Nd = 512; tr = t >> 4; tc = t & 15;
    }
    int kr = tid >> 3, nc4 = (tid & 7) * 4;
    float4_t v = *(const float4_t*)&src[(long)(tr * 32 + kr) * Nd + tc * 32 + nc4];
    for (int j = 0; j < 4; ++j) tile[kr][nc4 + j] = v[j];
    __syncthreads();
    int nr = tid >> 3, kc4 = (tid & 7) * 4;
    unsigned short tmp[4];
    for (int j = 0; j < 4; ++j) tmp[j] = f2bf_bits(tile[kc4 + j][nr]);
    uint2 uu;
    uu.x = (unsigned)tmp[0] | ((unsigned)tmp[1] << 16);
    uu.y = (unsigned)tmp[2] | ((unsigned)tmp[3] << 16);
    *(uint2*)&dst[(long)(tc * 32 + nr) * Kd + tr * 32 + kc4] = uu;
}

// ---------------------------------------------------------------------------
// Token embedding gather + rank-2 delta projection
// ---------------------------------------------------------------------------
__global__ __launch_bounds__(256) void embed_kernel(
    const int* __restrict__ tokens, const float* __restrict__ emb,
    const float* __restrict__ w_in, const float* __restrict__ w_out,
    float* __restrict__ x, float* __restrict__ delta)
{
    int bt = blockIdx.x;
    int d  = threadIdx.x;
    int tok = tokens[bt];
    float e = emb[tok * D_ + d];
    x[(long)bt * D_ + d] = e;

    __shared__ float r0s[256], r1s[256];
    r0s[d] = e * w_in[d * 2 + 0];
    r1s[d] = e * w_in[d * 2 + 1];
    __syncthreads();
    for (int off = 128; off > 0; off >>= 1) {
        if (d < off) { r0s[d] += r0s[d + off]; r1s[d] += r1s[d + off]; }
        __syncthreads();
    }
    float r0 = r0s[0], r1 = r1s[0];
    if (d < H_ * NB_) {
        delta[(long)bt * (H_ * NB_) + d] =
            r0 * w_out[d] + r1 * w_out[H_ * NB_ + d];
    }
}

// ---------------------------------------------------------------------------
// cumsum over T per (b, channel) + cos/sin
// ---------------------------------------------------------------------------
__global__ __launch_bounds__(256) void cumsum_kernel(
    const float* __restrict__ delta, const float* __restrict__ omega,
    float* __restrict__ cosb, float* __restrict__ sinb)
{
    int c = blockIdx.x & (H_ * NB_ - 1);
    int b = blockIdx.x >> 7;
    int tid = threadIdx.x;
    float om = omega[c];
    int h = c >> 5, nb = c & (NB_ - 1);

    float vals[8];
    float s = 0.0f;
    for (int i = 0; i < 8; ++i) {
        int t = tid * 8 + i;
        vals[i] = delta[((long)b * T_ + t) * (H_ * NB_) + c];
        s += vals[i];
    }
    __shared__ float sc[256];
    sc[tid] = s;
    __syncthreads();
    for (int off = 1; off < 256; off <<= 1) {
        float v = (tid >= off) ? sc[tid - off] : 0.0f;
        __syncthreads();
        sc[tid] += v;
        __syncthreads();
    }
    float run = sc[tid] - s;
    for (int i = 0; i < 8; ++i) {
        run += vals[i];
        float ang = run * om;
        int t = tid * 8 + i;
        long oi = ((long)(b * H_ + h) * T_ + t) * NB_ + nb;
        cosb[oi] = cosf(ang);
        sinb[oi] = sinf(ang);
    }
}

// ---------------------------------------------------------------------------
// LayerNorm (fp32 in) -> bf16 out
// ---------------------------------------------------------------------------
__global__ __launch_bounds__(256) void ln_kernel(
    const float* __restrict__ x, const float* __restrict__ g,
    const float* __restrict__ b, unsigned short* __restrict__ out)
{
    int row = blockIdx.x;
    int d = threadIdx.x;
    float v = x[(long)row * D_ + d];
    __shared__ float ss[256], sq[256];
    ss[d] = v; sq[d] = v * v;
    __syncthreads();
    for (int off = 128; off > 0; off >>= 1) {
        if (d < off) { ss[d] += ss[d + off]; sq[d] += sq[d + off]; }
        __syncthreads();
    }
    float mu  = ss[0] * (1.0f / D_);
    float var = sq[0] * (1.0f / D_) - mu * mu;
    float inv = rsqrtf(var + 1e-5f);
    out[(long)row * D_ + d] = f2bf_bits((v - mu) * inv * g[d] + b[d]);
}

// ---------------------------------------------------------------------------
// MFMA GEMM: C[M,N] = A[M,K](bf16) @ Bt[N,K](bf16)^T + bias.
// 64x64 tile, BK=64, 4 waves x (16x64 strip), 16x16x32 MFMA.
// mode 0: fp32 out, row-major, bias per col, optional res add + gelu
// mode 1: bf16 out, row-major, bias per col, optional gelu
// mode 2: bf16 out, row-major, bias per ROW (for V^T via swapped operands)
// mode 3: bf16 out in (B,H,T,DH) layout with RoPE applied + qscale folded
// ---------------------------------------------------------------------------
__global__ __launch_bounds__(256) void gemm_mfma(
    const unsigned short* __restrict__ A, const unsigned short* __restrict__ Bt,
    const float* __restrict__ bias, const float* __restrict__ res,
    float* __restrict__ outf, unsigned short* __restrict__ outb,
    const float* __restrict__ ropeC, const float* __restrict__ ropeS,
    float qscale, int M, int N, int K, int mode, int do_gelu)
{
    __shared__ __align__(16) short As[64 * 72];
    __shared__ __align__(16) short Bs[64 * 72];
    int tid = threadIdx.x;
    int w = tid >> 6, lane = tid & 63, quad = lane >> 4, l16 = lane & 15;
    int n0 = blockIdx.x * 64, r0 = blockIdx.y * 64;

    float4_t acc[4];
    for (int nt = 0; nt < 4; ++nt) acc[nt] = (float4_t){0.f, 0.f, 0.f, 0.f};

    for (int k0 = 0; k0 < K; k0 += 64) {
        __syncthreads();
        for (int i = 0; i < 2; ++i) {
            int e = tid + 256 * i;
            int r = e >> 3, c8 = e & 7;
            *(short8_t*)&As[r * 72 + c8 * 8] =
                *(const short8_t*)&A[(long)(r0 + r) * K + k0 + c8 * 8];
            *(short8_t*)&Bs[r * 72 + c8 * 8] =
                *(const short8_t*)&Bt[(long)(n0 + r) * K + k0 + c8 * 8];
        }
        __syncthreads();
        for (int kq = 0; kq < 2; ++kq) {
            short8_t a = *(const short8_t*)&As[(w * 16 + l16) * 72 + kq * 32 + quad * 8];
            for (int nt = 0; nt < 4; ++nt) {
                short8_t bfr = *(const short8_t*)&Bs[(nt * 16 + l16) * 72 + kq * 32 + quad * 8];
                acc[nt] = MFMA16(a, bfr, acc[nt]);
            }
        }
    }

    int h_head = n0 >> 6;   // valid for mode 3 (N==256, tiles are head-aligned)
    for (int nt = 0; nt < 4; ++nt) {
        int n = n0 + nt * 16 + l16;
        float bcol = (mode == 2) ? 0.0f : bias[n];
        for (int r = 0; r < 4; ++r) {
            int row = r0 + w * 16 + quad * 4 + r;
            float v = acc[nt][r] + ((mode == 2) ? bias[row] : bcol);
            if (res) v += res[(long)row * N + n];
            if (do_gelu) v = 0.5f * v * (1.0f + erff(v * 0.70710678118654752f));
            if (mode == 0) {
                outf[(long)row * N + n] = v;
            } else if (mode == 1 || mode == 2) {
                outb[(long)row * N + n] = f2bf_bits(v);
            } else {  // mode 3: rope (pairs are adjacent columns -> lane^1)
                float vp = __shfl_xor(v, 1);
                int bb = row >> 11, t = row & (T_ - 1);
                int nb = (n & 63) >> 1;
                long ci = ((long)(bb * H_ + h_head) * T_ + t) * NB_ + nb;
                float c = ropeC[ci], sn = ropeS[ci];
                float ov = (l16 & 1) ? (vp * sn + v * c) : (v * c - vp * sn);
                outb[((long)(bb * H_ + h_head) * T_ + t) * DH_ + (n & 63)] =
                    f2bf_bits(ov * qscale);
            }
        }
    }
}

// ---------------------------------------------------------------------------
// Split-K MFMA flash attention (flash-decoding style).
// Block = 4 waves, one q-tile (64 rows) x one chunk of up to 16 k-tiles.
// qt < 16: single chunk -> write final bf16 O directly.
// qt >= 16: two chunks (c=0: kt 0..15, c=1: kt 16..qt) -> fp32 partials
//           (o, m, l) merged by attn_merge.
// 768 active blocks, uniform <=16 iterations -> ~3 blocks/CU resident,
// overlapping latency chains per SIMD (vs 1 before).
// ---------------------------------------------------------------------------
__global__ __launch_bounds__(256) void attn_part(
    const unsigned short* __restrict__ Qb, const unsigned short* __restrict__ Kb,
    const unsigned short* __restrict__ Vt, unsigned short* __restrict__ O,
    float* __restrict__ po, float* __restrict__ pm, float* __restrict__ pl)
{
    __shared__ __align__(16) short Ps[4][16 * 72];

    int bx = blockIdx.x;
    int bh = bx & 15;
    int qt = (bx >> 4) & 31;
    int c  = bx >> 9;                 // 0 or 1
    if (c && qt < 16) return;         // chunk 1 only exists for qt >= 16

    int tid = threadIdx.x;
    int w = tid >> 6, lane = tid & 63;
    int quad = lane >> 4, l16 = lane & 15;
    int q0 = qt * 64;
    int b = bh >> 2, h = bh & 3;
    int kstart = c * 16;
    int kend = min(qt, kstart + 15);

    // Q A-frags, held all kernel (scale 1/8 already folded in)
    const unsigned short* qp =
        Qb + ((long)bh * T_ + q0 + w * 16 + l16) * DH_ + quad * 8;
    short8_t aq[2];
    aq[0] = *(const short8_t*)qp;
    aq[1] = *(const short8_t*)(qp + 32);

    const unsigned short* kb_base = Kb + (long)bh * T_ * DH_ + quad * 8;
    const unsigned short* vt_base =
        Vt + (long)h * DH_ * (B_ * T_) + (long)b * T_ + quad * 8;

    float m_r[4], l_r[4];
    for (int r = 0; r < 4; ++r) { m_r[r] = -3.0e38f; l_r[r] = 0.0f; }
    float4_t o[4];
    for (int nt = 0; nt < 4; ++nt) o[nt] = (float4_t){0.f, 0.f, 0.f, 0.f};

    // prefetch K fragments for kt=kstart
    short8_t kf[4][2];
    for (int nt = 0; nt < 4; ++nt) {
        const unsigned short* kp =
            kb_base + (long)(kstart * 64 + nt * 16 + l16) * DH_;
        kf[nt][0] = *(const short8_t*)kp;
        kf[nt][1] = *(const short8_t*)(kp + 32);
    }

    for (int kt = kstart; kt <= kend; ++kt) {
        int k0 = kt * 64;

        // V fragments for this tile: issue early, consume after softmax
        short8_t vb[4][2];
        for (int nt = 0; nt < 4; ++nt)
            for (int kq = 0; kq < 2; ++kq)
                vb[nt][kq] = *(const short8_t*)(
                    vt_base + (long)(nt * 16 + l16) * (B_ * T_) + k0 + kq * 32);

        // S = Q K^T from prefetched K fragments
        float4_t s[4];
        for (int nt = 0; nt < 4; ++nt) {
            float4_t sa = (float4_t){0.f, 0.f, 0.f, 0.f};
            sa = MFMA16(aq[0], kf[nt][0], sa);
            sa = MFMA16(aq[1], kf[nt][1], sa);
            s[nt] = sa;
        }

        // prefetch K fragments for kt+1 (hidden under softmax)
        if (kt < kend) {
            for (int nt = 0; nt < 4; ++nt) {
                const unsigned short* kp =
                    kb_base + (long)(k0 + 64 + nt * 16 + l16) * DH_;
                kf[nt][0] = *(const short8_t*)kp;
                kf[nt][1] = *(const short8_t*)(kp + 32);
            }
        }

        // causal mask + row max (C layout: row=quad*4+r, col=l16)
        bool diag = (kt == qt);
        float mt[4];
        for (int r = 0; r < 4; ++r) mt[r] = -3.0e38f;
        for (int nt = 0; nt < 4; ++nt) {
            int kcol = k0 + nt * 16 + l16;
            for (int r = 0; r < 4; ++r) {
                float sv = s[nt][r];
                if (diag && kcol > q0 + w * 16 + quad * 4 + r) sv = -3.0e38f;
                s[nt][r] = sv;
                mt[r] = fmaxf(mt[r], sv);
            }
        }
        for (int off = 1; off < 16; off <<= 1)
            for (int r = 0; r < 4; ++r)
                mt[r] = fmaxf(mt[r], __shfl_xor(mt[r], off));

        float alpha[4];
        for (int r = 0; r < 4; ++r) {
            float mn = fmaxf(m_r[r], mt[r]);
            alpha[r] = __expf(m_r[r] - mn);
            m_r[r] = mn;
        }

        float lt[4] = {0.f, 0.f, 0.f, 0.f};
        for (int nt = 0; nt < 4; ++nt) {
            for (int r = 0; r < 4; ++r) {
                float pv = __expf(s[nt][r] - m_r[r]);
                lt[r] += pv;
                Ps[w][(quad * 4 + r) * 72 + nt * 16 + l16] = (short)f2bf_bits(pv);
            }
        }
        for (int off = 1; off < 16; off <<= 1)
            for (int r = 0; r < 4; ++r)
                lt[r] += __shfl_xor(lt[r], off);
        for (int r = 0; r < 4; ++r) l_r[r] = l_r[r] * alpha[r] + lt[r];
        for (int nt = 0; nt < 4; ++nt)
            for (int r = 0; r < 4; ++r) o[nt][r] *= alpha[r];

        // O += P @ V  (wave-private P strip; V^T frags contiguous short8)
        for (int kq = 0; kq < 2; ++kq) {
            short8_t pa = *(const short8_t*)&Ps[w][l16 * 72 + kq * 32 + quad * 8];
            for (int nt = 0; nt < 4; ++nt)
                o[nt] = MFMA16(pa, vb[nt][kq], o[nt]);
        }
    }

    if (qt < 16) {
        // single-chunk: finalize directly
        for (int r = 0; r < 4; ++r) {
            float inv = 1.0f / l_r[r];
            int trow = q0 + w * 16 + quad * 4 + r;
            long orow = ((long)b * T_ + trow) * D_ + h * 64;
            for (int nt = 0; nt < 4; ++nt)
                O[orow + nt * 16 + l16] = f2bf_bits(o[nt][r] * inv);
        }
    } else {
        // write fp32 partial (o unnormalized, m, l)
        int task = bh * 16 + (qt - 16);
        long pbase = ((long)task * 2 + c) * 4096;
        for (int r = 0; r < 4; ++r) {
            int lrow = w * 16 + quad * 4 + r;
            for (int nt = 0; nt < 4; ++nt)
                po[pbase + (long)lrow * 64 + nt * 16 + l16] = o[nt][r];
            if (l16 == 0) {
                pm[(task * 2 + c) * 64 + lrow] = m_r[r];
                pl[(task * 2 + c) * 64 + lrow] = l_r[r];
            }
        }
    }
}

// ---------------------------------------------------------------------------
// Merge two split-K partials per (bh, qt>=16): O = sum_c e_c*o_c / sum_c e_c*l_c
// ---------------------------------------------------------------------------
__global__ __launch_bounds__(256) void attn_merge(
    const float* __restrict__ po, const float* __restrict__ pm,
    const float* __restrict__ pl, unsigned short* __restrict__ O)
{
    int bh = blockIdx.x;              // 0..15
    int qt = 16 + blockIdx.y;         // 16..31
    int tid = threadIdx.x;
    int r = tid >> 2;                 // 0..63
    int c0 = (tid & 3) * 16;

    int task = bh * 16 + (qt - 16);
    long p0 = ((long)task * 2 + 0) * 4096;
    long p1 = ((long)task * 2 + 1) * 4096;
    float m0 = pm[(task * 2 + 0) * 64 + r];
    float m1 = pm[(task * 2 + 1) * 64 + r];
    float l0 = pl[(task * 2 + 0) * 64 + r];
    float l1 = pl[(task * 2 + 1) * 64 + r];
    float M  = fmaxf(m0, m1);
    float e0 = __expf(m0 - M), e1 = __expf(m1 - M);
    float inv = 1.0f / (l0 * e0 + l1 * e1);

    int b = bh >> 2, h = bh & 3;
    int trow = qt * 64 + r;
    long orow = ((long)b * T_ + trow) * D_ + h * 64;
    for (int j = 0; j < 16; j += 4) {
        float4_t v0 = *(const float4_t*)&po[p0 + (long)r * 64 + c0 + j];
        float4_t v1 = *(const float4_t*)&po[p1 + (long)r * 64 + c0 + j];
        for (int k = 0; k < 4; ++k)
            O[orow + c0 + j + k] = f2bf_bits((v0[k] * e0 + v1[k] * e1) * inv);
    }
}

// ---------------------------------------------------------------------------
extern "C" void kernel_launch(void* const* d_in, const int* in_sizes, int n_in,
                              void* d_out, int out_size, void* d_ws, size_t ws_size,
                              hipStream_t stream)
{
    const int*   tokens    = (const int*)d_in[0];
    const float* token_emb = (const float*)d_in[1];
    const float* w_in      = (const float*)d_in[2];
    const float* w_out     = (const float*)d_in[3];
    const float* omega     = (const float*)d_in[4];
    const float* Wq        = (const float*)d_in[5];
    const float* bq        = (const float*)d_in[6];
    const float* Wk        = (const float*)d_in[7];
    const float* bk        = (const float*)d_in[8];
    const float* Wv        = (const float*)d_in[9];
    const float* bv        = (const float*)d_in[10];
    const float* Wo        = (const float*)d_in[11];
    const float* bo        = (const float*)d_in[12];
    const float* ln1_g     = (const float*)d_in[13];
    const float* ln1_b     = (const float*)d_in[14];
    const float* ln2_g     = (const float*)d_in[15];
    const float* ln2_b     = (const float*)d_in[16];
    const float* W1        = (const float*)d_in[17];
    const float* b1        = (const float*)d_in[18];
    const float* W2        = (const float*)d_in[19];
    const float* b2        = (const float*)d_in[20];
    const float* out_g     = (const float*)d_in[21];
    const float* out_b     = (const float*)d_in[22];
    const float* Wout      = (const float*)d_in[23];
    const float* bout      = (const float*)d_in[24];

    const long NTOK = (long)B_ * T_;  // 8192
    float* xbuf = (float*)d_ws;                       // fp32 residual stream 8MB
    float* cosb = xbuf + NTOK * D_;                   // (B,H,T,NB) fp32 4MB
    float* sinb = cosb + NTOK * H_ * NB_;             // 4MB
    float* dbuf = sinb + NTOK * H_ * NB_;             // (B,T,H*NB) fp32 4MB
    unsigned short* hbuf  = (unsigned short*)(dbuf + NTOK * H_ * NB_); // bf16 LN out 4MB
    unsigned short* obuf  = hbuf + NTOK * D_;         // bf16 attn out 4MB
    unsigned short* ffbuf = obuf + NTOK * D_;         // bf16 FFN mid 16MB
    unsigned short* qb16  = ffbuf + NTOK * DFF_;      // bf16 Q (B,H,T,DH) 4MB
    unsigned short* kb16  = qb16 + NTOK * D_;         // bf16 K (B,H,T,DH) 4MB
    unsigned short* vtb   = kb16 + NTOK * D_;         // bf16 V^T [H*DH][B*T] 4MB
    unsigned short* wqt   = vtb + NTOK * D_;          // transposed bf16 weights
    unsigned short* wkt   = wqt + 2 * 65536;
    unsigned short* wvt   = wkt + 2 * 65536;
    unsigned short* wot   = wvt + 2 * 65536;
    unsigned short* w1t   = wot + 2 * 65536;
    unsigned short* w2t   = w1t + 2 * 262144;
    unsigned short* woutt = w2t + 2 * 262144;
    float* po = (float*)(woutt + 131072);             // split-K partials 8.4MB
    float* pm = po + (long)512 * 4096;                // 512 partials x 64 rows
    float* pl = pm + 512 * 64;
    // total ~69 MB

    wt_kernel<<<1664, 256, 0, stream>>>(Wq, Wk, Wv, Wo, W1, W2, Wout,
                                        wqt, wkt, wvt, wot, w1t, w2t, woutt);
    embed_kernel<<<NTOK, 256, 0, stream>>>(tokens, token_emb, w_in, w_out, xbuf, dbuf);
    cumsum_kernel<<<B_ * H_ * NB_, 256, 0, stream>>>(dbuf, omega, cosb, sinb);

    for (int l = 0; l < NL_; ++l) {
        ln_kernel<<<NTOK, 256, 0, stream>>>(xbuf, ln1_g + l * D_, ln1_b + l * D_, hbuf);
        // Q: rope + 1/8 scale folded, bf16 attn layout
        gemm_mfma<<<dim3(4, 128), 256, 0, stream>>>(
            hbuf, wqt + (long)l * 65536, bq + l * D_, nullptr, nullptr, qb16,
            cosb, sinb, 0.125f, (int)NTOK, D_, D_, 3, 0);
        // K: rope folded, bf16 attn layout
        gemm_mfma<<<dim3(4, 128), 256, 0, stream>>>(
            hbuf, wkt + (long)l * 65536, bk + l * D_, nullptr, nullptr, kb16,
            cosb, sinb, 1.0f, (int)NTOK, D_, D_, 3, 0);
        // V^T via swapped operands: C[d][token] = sum_k Wv[k][d] h[token][k]
        gemm_mfma<<<dim3(128, 4), 256, 0, stream>>>(
            wvt + (long)l * 65536, hbuf, bv + l * D_, nullptr, nullptr, vtb,
            nullptr, nullptr, 0.f, D_, (int)NTOK, D_, 2, 0);
        attn_part<<<1024, 256, 0, stream>>>(qb16, kb16, vtb, obuf, po, pm, pl);
        attn_merge<<<dim3(16, 16), 256, 0, stream>>>(po, pm, pl, obuf);
        gemm_mfma<<<dim3(4, 128), 256, 0, stream>>>(
            obuf, wot + (long)l * 65536, bo + l * D_, xbuf, xbuf, nullptr,
            nullptr, nullptr, 0.f, (int)NTOK, D_, D_, 0, 0);
        ln_kernel<<<NTOK, 256, 0, stream>>>(xbuf, ln2_g + l * D_, ln2_b + l * D_, hbuf);
        gemm_mfma<<<dim3(16, 128), 256, 0, stream>>>(
            hbuf, w1t + (long)l * 262144, b1 + l * DFF_, nullptr, nullptr, ffbuf,
            nullptr, nullptr, 0.f, (int)NTOK, DFF_, D_, 1, 1);
        gemm_mfma<<<dim3(4, 128), 256, 0, stream>>>(
            ffbuf, w2t + (long)l * 262144, b2 + l * D_, xbuf, xbuf, nullptr,
            nullptr, nullptr, 0.f, (int)NTOK, D_, DFF_, 0, 0);
    }

    ln_kernel<<<NTOK, 256, 0, stream>>>(xbuf, out_g, out_b, hbuf);
    gemm_mfma<<<dim3(8, 128), 256, 0, stream>>>(
        hbuf, woutt, bout, nullptr, (float*)d_out, nullptr,
        nullptr, nullptr, 0.f, (int)NTOK, V_, D_, 0, 0);
}

// Round 4
// 519.037 us; speedup vs baseline: 1.1229x; 1.1229x over previous
//
#include <hip/hip_runtime.h>
#include <hip/hip_bf16.h>
#include <math.h>

#define B_   4
#define T_   2048
#define V_   512
#define D_   256
#define H_   4
#define DH_  64
#define NB_  32
#define DFF_ 1024
#define NL_  2

typedef __attribute__((ext_vector_type(8))) short short8_t;
typedef __attribute__((ext_vector_type(4))) float float4_t;

#define MFMA16(a,b,c) __builtin_amdgcn_mfma_f32_16x16x32_bf16(a,b,c,0,0,0)

__device__ __forceinline__ unsigned short f2bf_bits(float f) {
    unsigned u = __float_as_uint(f);
    u += 0x7fffu + ((u >> 16) & 1u);
    return (unsigned short)(u >> 16);
}

// ---------------------------------------------------------------------------
// Weight transpose+cast: W[K][N] fp32 -> Wt[N][K] bf16. One 32x32 tile/block.
// ---------------------------------------------------------------------------
__global__ __launch_bounds__(256) void wt_kernel(
    const float* __restrict__ Wq, const float* __restrict__ Wk,
    const float* __restrict__ Wv, const float* __restrict__ Wo,
    const float* __restrict__ W1, const float* __restrict__ W2,
    const float* __restrict__ Wout,
    unsigned short* __restrict__ wqt, unsigned short* __restrict__ wkt,
    unsigned short* __restrict__ wvt, unsigned short* __restrict__ wot,
    unsigned short* __restrict__ w1t, unsigned short* __restrict__ w2t,
    unsigned short* __restrict__ woutt)
{
    __shared__ float tile[32][33];
    int bx = blockIdx.x, tid = threadIdx.x;
    const float* src; unsigned short* dst; int Kd, Nd, tr, tc;
    if (bx < 512) {                    // Wq/Wk/Wv/Wo, 2 layers each, 256x256
        int am = bx >> 6, t = bx & 63;
        const float* s4[4] = {Wq, Wk, Wv, Wo};
        unsigned short* d4[4] = {wqt, wkt, wvt, wot};
        src = s4[am >> 1] + (long)(am & 1) * 65536;
        dst = d4[am >> 1] + (long)(am & 1) * 65536;
        Kd = 256; Nd = 256; tr = t >> 3; tc = t & 7;
    } else if (bx < 1024) {            // W1: 2 x (256x1024)
        int idx = bx - 512, mat = idx >> 8, t = idx & 255;
        src = W1 + (long)mat * 262144; dst = w1t + (long)mat * 262144;
        Kd = 256; Nd = 1024; tr = t >> 5; tc = t & 31;
    } else if (bx < 1536) {            // W2: 2 x (1024x256)
        int idx = bx - 1024, mat = idx >> 8, t = idx & 255;
        src = W2 + (long)mat * 262144; dst = w2t + (long)mat * 262144;
        Kd = 1024; Nd = 256; tr = t >> 3; tc = t & 7;
    } else {                           // Wout: 256x512
        int t = bx - 1536;
        src = Wout; dst = woutt; Kd = 256; Nd = 512; tr = t >> 4; tc = t & 15;
    }
    int kr = tid >> 3, nc4 = (tid & 7) * 4;
    float4_t v = *(const float4_t*)&src[(long)(tr * 32 + kr) * Nd + tc * 32 + nc4];
    for (int j = 0; j < 4; ++j) tile[kr][nc4 + j] = v[j];
    __syncthreads();
    int nr = tid >> 3, kc4 = (tid & 7) * 4;
    unsigned short tmp[4];
    for (int j = 0; j < 4; ++j) tmp[j] = f2bf_bits(tile[kc4 + j][nr]);
    uint2 uu;
    uu.x = (unsigned)tmp[0] | ((unsigned)tmp[1] << 16);
    uu.y = (unsigned)tmp[2] | ((unsigned)tmp[3] << 16);
    *(uint2*)&dst[(long)(tc * 32 + nr) * Kd + tr * 32 + kc4] = uu;
}

// ---------------------------------------------------------------------------
// Token embedding gather + rank-2 delta projection
// ---------------------------------------------------------------------------
__global__ __launch_bounds__(256) void embed_kernel(
    const int* __restrict__ tokens, const float* __restrict__ emb,
    const float* __restrict__ w_in, const float* __restrict__ w_out,
    float* __restrict__ x, float* __restrict__ delta)
{
    int bt = blockIdx.x;
    int d  = threadIdx.x;
    int tok = tokens[bt];
    float e = emb[tok * D_ + d];
    x[(long)bt * D_ + d] = e;

    __shared__ float r0s[256], r1s[256];
    r0s[d] = e * w_in[d * 2 + 0];
    r1s[d] = e * w_in[d * 2 + 1];
    __syncthreads();
    for (int off = 128; off > 0; off >>= 1) {
        if (d < off) { r0s[d] += r0s[d + off]; r1s[d] += r1s[d + off]; }
        __syncthreads();
    }
    float r0 = r0s[0], r1 = r1s[0];
    if (d < H_ * NB_) {
        delta[(long)bt * (H_ * NB_) + d] =
            r0 * w_out[d] + r1 * w_out[H_ * NB_ + d];
    }
}

// ---------------------------------------------------------------------------
// cumsum over T per (b, channel) + cos/sin
// ---------------------------------------------------------------------------
__global__ __launch_bounds__(256) void cumsum_kernel(
    const float* __restrict__ delta, const float* __restrict__ omega,
    float* __restrict__ cosb, float* __restrict__ sinb)
{
    int c = blockIdx.x & (H_ * NB_ - 1);
    int b = blockIdx.x >> 7;
    int tid = threadIdx.x;
    float om = omega[c];
    int h = c >> 5, nb = c & (NB_ - 1);

    float vals[8];
    float s = 0.0f;
    for (int i = 0; i < 8; ++i) {
        int t = tid * 8 + i;
        vals[i] = delta[((long)b * T_ + t) * (H_ * NB_) + c];
        s += vals[i];
    }
    __shared__ float sc[256];
    sc[tid] = s;
    __syncthreads();
    for (int off = 1; off < 256; off <<= 1) {
        float v = (tid >= off) ? sc[tid - off] : 0.0f;
        __syncthreads();
        sc[tid] += v;
        __syncthreads();
    }
    float run = sc[tid] - s;
    for (int i = 0; i < 8; ++i) {
        run += vals[i];
        float ang = run * om;
        int t = tid * 8 + i;
        long oi = ((long)(b * H_ + h) * T_ + t) * NB_ + nb;
        cosb[oi] = cosf(ang);
        sinb[oi] = sinf(ang);
    }
}

// ---------------------------------------------------------------------------
// LayerNorm (fp32 in) -> bf16 out
// ---------------------------------------------------------------------------
__global__ __launch_bounds__(256) void ln_kernel(
    const float* __restrict__ x, const float* __restrict__ g,
    const float* __restrict__ b, unsigned short* __restrict__ out)
{
    int row = blockIdx.x;
    int d = threadIdx.x;
    float v = x[(long)row * D_ + d];
    __shared__ float ss[256], sq[256];
    ss[d] = v; sq[d] = v * v;
    __syncthreads();
    for (int off = 128; off > 0; off >>= 1) {
        if (d < off) { ss[d] += ss[d + off]; sq[d] += sq[d + off]; }
        __syncthreads();
    }
    float mu  = ss[0] * (1.0f / D_);
    float var = sq[0] * (1.0f / D_) - mu * mu;
    float inv = rsqrtf(var + 1e-5f);
    out[(long)row * D_ + d] = f2bf_bits((v - mu) * inv * g[d] + b[d]);
}

// ---------------------------------------------------------------------------
// MFMA GEMM: C[M,N] = A[M,K](bf16) @ Bt[N,K](bf16)^T + bias.
// 64x64 tile, BK=64, 4 waves x (16x64 strip), 16x16x32 MFMA.
// mode 0: fp32 out, row-major, bias per col, optional res add + gelu
// mode 1: bf16 out, row-major, bias per col, optional gelu
// mode 2: bf16 out, row-major, bias per ROW (for V^T via swapped operands)
// mode 3: bf16 out in (B,H,T,DH) layout with RoPE applied + qscale folded
// ---------------------------------------------------------------------------
__global__ __launch_bounds__(256) void gemm_mfma(
    const unsigned short* __restrict__ A, const unsigned short* __restrict__ Bt,
    const float* __restrict__ bias, const float* __restrict__ res,
    float* __restrict__ outf, unsigned short* __restrict__ outb,
    const float* __restrict__ ropeC, const float* __restrict__ ropeS,
    float qscale, int M, int N, int K, int mode, int do_gelu)
{
    __shared__ __align__(16) short As[64 * 72];
    __shared__ __align__(16) short Bs[64 * 72];
    int tid = threadIdx.x;
    int w = tid >> 6, lane = tid & 63, quad = lane >> 4, l16 = lane & 15;
    int n0 = blockIdx.x * 64, r0 = blockIdx.y * 64;

    float4_t acc[4];
    for (int nt = 0; nt < 4; ++nt) acc[nt] = (float4_t){0.f, 0.f, 0.f, 0.f};

    for (int k0 = 0; k0 < K; k0 += 64) {
        __syncthreads();
        for (int i = 0; i < 2; ++i) {
            int e = tid + 256 * i;
            int r = e >> 3, c8 = e & 7;
            *(short8_t*)&As[r * 72 + c8 * 8] =
                *(const short8_t*)&A[(long)(r0 + r) * K + k0 + c8 * 8];
            *(short8_t*)&Bs[r * 72 + c8 * 8] =
                *(const short8_t*)&Bt[(long)(n0 + r) * K + k0 + c8 * 8];
        }
        __syncthreads();
        for (int kq = 0; kq < 2; ++kq) {
            short8_t a = *(const short8_t*)&As[(w * 16 + l16) * 72 + kq * 32 + quad * 8];
            for (int nt = 0; nt < 4; ++nt) {
                short8_t bfr = *(const short8_t*)&Bs[(nt * 16 + l16) * 72 + kq * 32 + quad * 8];
                acc[nt] = MFMA16(a, bfr, acc[nt]);
            }
        }
    }

    int h_head = n0 >> 6;   // valid for mode 3 (N==256, tiles are head-aligned)
    for (int nt = 0; nt < 4; ++nt) {
        int n = n0 + nt * 16 + l16;
        float bcol = (mode == 2) ? 0.0f : bias[n];
        for (int r = 0; r < 4; ++r) {
            int row = r0 + w * 16 + quad * 4 + r;
            float v = acc[nt][r] + ((mode == 2) ? bias[row] : bcol);
            if (res) v += res[(long)row * N + n];
            if (do_gelu) v = 0.5f * v * (1.0f + erff(v * 0.70710678118654752f));
            if (mode == 0) {
                outf[(long)row * N + n] = v;
            } else if (mode == 1 || mode == 2) {
                outb[(long)row * N + n] = f2bf_bits(v);
            } else {  // mode 3: rope (pairs are adjacent columns -> lane^1)
                float vp = __shfl_xor(v, 1);
                int bb = row >> 11, t = row & (T_ - 1);
                int nb = (n & 63) >> 1;
                long ci = ((long)(bb * H_ + h_head) * T_ + t) * NB_ + nb;
                float c = ropeC[ci], sn = ropeS[ci];
                float ov = (l16 & 1) ? (vp * sn + v * c) : (v * c - vp * sn);
                outb[((long)(bb * H_ + h_head) * T_ + t) * DH_ + (n & 63)] =
                    f2bf_bits(ov * qscale);
            }
        }
    }
}

// ---------------------------------------------------------------------------
// MFMA flash attention, all-bf16 inputs, zero barriers.
// 8 waves/block: waves 0-3 handle q-tile p, waves 4-7 handle q-tile 31-p
// (heavy+light share each SIMD; per-SIMD work uniform = 33 k-tiles).
//
// SWAPPED QK^T: S^T = MFMA(K_frag, Q_frag) so each lane holds S for ONE
// query (q = l16), k = nt*16 + quad*4 + r. Softmax reduction over k is
// 15 in-lane VALU ops + 2 shfl_xor (quad groups) -- vs 32 bpermutes for
// the row-spread layout. m, l are per-lane scalars; alpha/l redistributed
// to the C-layout rows (quad*4+r) with 4 independent shuffles.
// P -> wave-private LDS strip (P[q=l16][k], same PV read path as before).
// ---------------------------------------------------------------------------
__global__ __launch_bounds__(512) void attn_mfma(
    const unsigned short* __restrict__ Qb, const unsigned short* __restrict__ Kb,
    const unsigned short* __restrict__ Vt, unsigned short* __restrict__ O)
{
    __shared__ __align__(16) short Ps[8][16 * 72];

    int tid = threadIdx.x;
    int w = tid >> 6, lane = tid & 63;
    int quad = lane >> 4, l16 = lane & 15;
    int bh = blockIdx.x & 15;
    int p  = blockIdx.x >> 4;            // 0..15
    int qt = (w < 4) ? p : 31 - p;       // heavy+light share each SIMD
    int wr = w & 3;                      // 16-row group within the 64-row tile
    int q0 = qt * 64;
    int b = bh >> 2, h = bh & 3;
    int qglob = q0 + wr * 16 + l16;      // this lane's query row

    // Q A/B-frags, held all kernel (scale 1/8 already folded in)
    const unsigned short* qp =
        Qb + ((long)bh * T_ + q0 + wr * 16 + l16) * DH_ + quad * 8;
    short8_t aq[2];
    aq[0] = *(const short8_t*)qp;
    aq[1] = *(const short8_t*)(qp + 32);

    const unsigned short* kb_base = Kb + (long)bh * T_ * DH_ + quad * 8;
    const unsigned short* vt_base =
        Vt + (long)h * DH_ * (B_ * T_) + (long)b * T_ + quad * 8;

    float m_r = -3.0e38f, l_r = 0.0f;    // per-lane (query = l16) stats
    float4_t o[4];
    for (int nt = 0; nt < 4; ++nt) o[nt] = (float4_t){0.f, 0.f, 0.f, 0.f};

    // prefetch K fragments for kt=0
    short8_t kf[4][2];
    for (int nt = 0; nt < 4; ++nt) {
        const unsigned short* kp = kb_base + (long)(nt * 16 + l16) * DH_;
        kf[nt][0] = *(const short8_t*)kp;
        kf[nt][1] = *(const short8_t*)(kp + 32);
    }

    for (int kt = 0; kt <= qt; ++kt) {
        int k0 = kt * 64;

        // V fragments for this tile: issue early, consume after softmax
        short8_t vb[4][2];
        for (int nt = 0; nt < 4; ++nt)
            for (int kq = 0; kq < 2; ++kq)
                vb[nt][kq] = *(const short8_t*)(
                    vt_base + (long)(nt * 16 + l16) * (B_ * T_) + k0 + kq * 32);

        // S^T = K Q^T: lane holds S[k = nt*16+quad*4+r][q = l16-query]
        float4_t st[4];
        for (int nt = 0; nt < 4; ++nt) {
            float4_t sa = (float4_t){0.f, 0.f, 0.f, 0.f};
            sa = MFMA16(kf[nt][0], aq[0], sa);
            sa = MFMA16(kf[nt][1], aq[1], sa);
            st[nt] = sa;
        }

        // prefetch K fragments for kt+1 (hidden under softmax)
        if (kt < qt) {
            for (int nt = 0; nt < 4; ++nt) {
                const unsigned short* kp =
                    kb_base + (long)(k0 + 64 + nt * 16 + l16) * DH_;
                kf[nt][0] = *(const short8_t*)kp;
                kf[nt][1] = *(const short8_t*)(kp + 32);
            }
        }

        // causal mask + in-lane max over 16 k values (this lane's k slice)
        bool diag = (kt == qt);
        float mt = -3.0e38f;
        for (int nt = 0; nt < 4; ++nt) {
            for (int r = 0; r < 4; ++r) {
                float sv = st[nt][r];
                if (diag && (k0 + nt * 16 + quad * 4 + r) > qglob) sv = -3.0e38f;
                st[nt][r] = sv;
                mt = fmaxf(mt, sv);
            }
        }
        // cross-quad max: lanes {l16, l16+16, l16+32, l16+48} -> full 64-k max
        mt = fmaxf(mt, __shfl_xor(mt, 16));
        mt = fmaxf(mt, __shfl_xor(mt, 32));

        float mn = fmaxf(m_r, mt);
        float alpha = __expf(m_r - mn);
        m_r = mn;

        // redistribute alpha to C-layout rows (row = quad*4+r <- lane r' = q)
        float ac[4];
        for (int r = 0; r < 4; ++r) ac[r] = __shfl(alpha, quad * 4 + r);

        // exp + in-lane sum + P write (P[q=l16][k])
        float lt = 0.0f;
        for (int nt = 0; nt < 4; ++nt) {
            for (int r = 0; r < 4; ++r) {
                float pv = __expf(st[nt][r] - m_r);
                lt += pv;
                Ps[w][l16 * 72 + nt * 16 + quad * 4 + r] = (short)f2bf_bits(pv);
            }
        }
        lt += __shfl_xor(lt, 16);
        lt += __shfl_xor(lt, 32);
        l_r = l_r * alpha + lt;

        for (int nt = 0; nt < 4; ++nt)
            for (int r = 0; r < 4; ++r) o[nt][r] *= ac[r];

        // O += P @ V  (wave-private P strip; V^T frags contiguous short8)
        for (int kq = 0; kq < 2; ++kq) {
            short8_t pa = *(const short8_t*)&Ps[w][l16 * 72 + kq * 32 + quad * 8];
            for (int nt = 0; nt < 4; ++nt)
                o[nt] = MFMA16(pa, vb[nt][kq], o[nt]);
        }
    }

    // final normalize: l for row quad*4+r lives in lane l16 = quad*4+r
    float linv[4];
    for (int r = 0; r < 4; ++r) linv[r] = __shfl(l_r, quad * 4 + r);
    for (int r = 0; r < 4; ++r) {
        float inv = 1.0f / linv[r];
        int trow = q0 + wr * 16 + quad * 4 + r;
        long orow = ((long)b * T_ + trow) * D_ + h * 64;
        for (int nt = 0; nt < 4; ++nt)
            O[orow + nt * 16 + l16] = f2bf_bits(o[nt][r] * inv);
    }
}

// ---------------------------------------------------------------------------
extern "C" void kernel_launch(void* const* d_in, const int* in_sizes, int n_in,
                              void* d_out, int out_size, void* d_ws, size_t ws_size,
                              hipStream_t stream)
{
    const int*   tokens    = (const int*)d_in[0];
    const float* token_emb = (const float*)d_in[1];
    const float* w_in      = (const float*)d_in[2];
    const float* w_out     = (const float*)d_in[3];
    const float* omega     = (const float*)d_in[4];
    const float* Wq        = (const float*)d_in[5];
    const float* bq        = (const float*)d_in[6];
    const float* Wk        = (const float*)d_in[7];
    const float* bk        = (const float*)d_in[8];
    const float* Wv        = (const float*)d_in[9];
    const float* bv        = (const float*)d_in[10];
    const float* Wo        = (const float*)d_in[11];
    const float* bo        = (const float*)d_in[12];
    const float* ln1_g     = (const float*)d_in[13];
    const float* ln1_b     = (const float*)d_in[14];
    const float* ln2_g     = (const float*)d_in[15];
    const float* ln2_b     = (const float*)d_in[16];
    const float* W1        = (const float*)d_in[17];
    const float* b1        = (const float*)d_in[18];
    const float* W2        = (const float*)d_in[19];
    const float* b2        = (const float*)d_in[20];
    const float* out_g     = (const float*)d_in[21];
    const float* out_b     = (const float*)d_in[22];
    const float* Wout      = (const float*)d_in[23];
    const float* bout      = (const float*)d_in[24];

    const long NTOK = (long)B_ * T_;  // 8192
    float* xbuf = (float*)d_ws;                       // fp32 residual stream 8MB
    float* cosb = xbuf + NTOK * D_;                   // (B,H,T,NB) fp32 4MB
    float* sinb = cosb + NTOK * H_ * NB_;             // 4MB
    float* dbuf = sinb + NTOK * H_ * NB_;             // (B,T,H*NB) fp32 4MB
    unsigned short* hbuf  = (unsigned short*)(dbuf + NTOK * H_ * NB_); // bf16 LN out 4MB
    unsigned short* obuf  = hbuf + NTOK * D_;         // bf16 attn out 4MB
    unsigned short* ffbuf = obuf + NTOK * D_;         // bf16 FFN mid 16MB
    unsigned short* qb16  = ffbuf + NTOK * DFF_;      // bf16 Q (B,H,T,DH) 4MB
    unsigned short* kb16  = qb16 + NTOK * D_;         // bf16 K (B,H,T,DH) 4MB
    unsigned short* vtb   = kb16 + NTOK * D_;         // bf16 V^T [H*DH][B*T] 4MB
    unsigned short* wqt   = vtb + NTOK * D_;          // transposed bf16 weights
    unsigned short* wkt   = wqt + 2 * 65536;
    unsigned short* wvt   = wkt + 2 * 65536;
    unsigned short* wot   = wvt + 2 * 65536;
    unsigned short* w1t   = wot + 2 * 65536;
    unsigned short* w2t   = w1t + 2 * 262144;
    unsigned short* woutt = w2t + 2 * 262144;
    // total ~60 MB

    wt_kernel<<<1664, 256, 0, stream>>>(Wq, Wk, Wv, Wo, W1, W2, Wout,
                                        wqt, wkt, wvt, wot, w1t, w2t, woutt);
    embed_kernel<<<NTOK, 256, 0, stream>>>(tokens, token_emb, w_in, w_out, xbuf, dbuf);
    cumsum_kernel<<<B_ * H_ * NB_, 256, 0, stream>>>(dbuf, omega, cosb, sinb);

    for (int l = 0; l < NL_; ++l) {
        ln_kernel<<<NTOK, 256, 0, stream>>>(xbuf, ln1_g + l * D_, ln1_b + l * D_, hbuf);
        // Q: rope + 1/8 scale folded, bf16 attn layout
        gemm_mfma<<<dim3(4, 128), 256, 0, stream>>>(
            hbuf, wqt + (long)l * 65536, bq + l * D_, nullptr, nullptr, qb16,
            cosb, sinb, 0.125f, (int)NTOK, D_, D_, 3, 0);
        // K: rope folded, bf16 attn layout
        gemm_mfma<<<dim3(4, 128), 256, 0, stream>>>(
            hbuf, wkt + (long)l * 65536, bk + l * D_, nullptr, nullptr, kb16,
            cosb, sinb, 1.0f, (int)NTOK, D_, D_, 3, 0);
        // V^T via swapped operands: C[d][token] = sum_k Wv[k][d] h[token][k]
        gemm_mfma<<<dim3(128, 4), 256, 0, stream>>>(
            wvt + (long)l * 65536, hbuf, bv + l * D_, nullptr, nullptr, vtb,
            nullptr, nullptr, 0.f, D_, (int)NTOK, D_, 2, 0);
        attn_mfma<<<256, 512, 0, stream>>>(qb16, kb16, vtb, obuf);
        gemm_mfma<<<dim3(4, 128), 256, 0, stream>>>(
            obuf, wot + (long)l * 65536, bo + l * D_, xbuf, xbuf, nullptr,
            nullptr, nullptr, 0.f, (int)NTOK, D_, D_, 0, 0);
        ln_kernel<<<NTOK, 256, 0, stream>>>(xbuf, ln2_g + l * D_, ln2_b + l * D_, hbuf);
        gemm_mfma<<<dim3(16, 128), 256, 0, stream>>>(
            hbuf, w1t + (long)l * 262144, b1 + l * DFF_, nullptr, nullptr, ffbuf,
            nullptr, nullptr, 0.f, (int)NTOK, DFF_, D_, 1, 1);
        gemm_mfma<<<dim3(4, 128), 256, 0, stream>>>(
            ffbuf, w2t + (long)l * 262144, b2 + l * D_, xbuf, xbuf, nullptr,
            nullptr, nullptr, 0.f, (int)NTOK, D_, DFF_, 0, 0);
    }

    ln_kernel<<<NTOK, 256, 0, stream>>>(xbuf, out_g, out_b, hbuf);
    gemm_mfma<<<dim3(8, 128), 256, 0, stream>>>(
        hbuf, woutt, bout, nullptr, (float*)d_out, nullptr,
        nullptr, nullptr, 0.f, (int)NTOK, V_, D_, 0, 0);
}

// Round 5
// 518.991 us; speedup vs baseline: 1.1230x; 1.0001x over previous
//
#include <hip/hip_runtime.h>
#include <hip/hip_bf16.h>
#include <math.h>

#define B_   4
#define T_   2048
#define V_   512
#define D_   256
#define H_   4
#define DH_  64
#define NB_  32
#define DFF_ 1024
#define NL_  2

typedef __attribute__((ext_vector_type(8))) short short8_t;
typedef __attribute__((ext_vector_type(4))) float float4_t;

#define MFMA16(a,b,c) __builtin_amdgcn_mfma_f32_16x16x32_bf16(a,b,c,0,0,0)

__device__ __forceinline__ unsigned short f2bf_bits(float f) {
    unsigned u = __float_as_uint(f);
    u += 0x7fffu + ((u >> 16) & 1u);
    return (unsigned short)(u >> 16);
}

// ---------------------------------------------------------------------------
// Weight transpose+cast: W[K][N] fp32 -> Wt[N][K] bf16. One 32x32 tile/block.
// ---------------------------------------------------------------------------
__global__ __launch_bounds__(256) void wt_kernel(
    const float* __restrict__ Wq, const float* __restrict__ Wk,
    const float* __restrict__ Wv, const float* __restrict__ Wo,
    const float* __restrict__ W1, const float* __restrict__ W2,
    const float* __restrict__ Wout,
    unsigned short* __restrict__ wqt, unsigned short* __restrict__ wkt,
    unsigned short* __restrict__ wvt, unsigned short* __restrict__ wot,
    unsigned short* __restrict__ w1t, unsigned short* __restrict__ w2t,
    unsigned short* __restrict__ woutt)
{
    __shared__ float tile[32][33];
    int bx = blockIdx.x, tid = threadIdx.x;
    const float* src; unsigned short* dst; int Kd, Nd, tr, tc;
    if (bx < 512) {                    // Wq/Wk/Wv/Wo, 2 layers each, 256x256
        int am = bx >> 6, t = bx & 63;
        const float* s4[4] = {Wq, Wk, Wv, Wo};
        unsigned short* d4[4] = {wqt, wkt, wvt, wot};
        src = s4[am >> 1] + (long)(am & 1) * 65536;
        dst = d4[am >> 1] + (long)(am & 1) * 65536;
        Kd = 256; Nd = 256; tr = t >> 3; tc = t & 7;
    } else if (bx < 1024) {            // W1: 2 x (256x1024)
        int idx = bx - 512, mat = idx >> 8, t = idx & 255;
        src = W1 + (long)mat * 262144; dst = w1t + (long)mat * 262144;
        Kd = 256; Nd = 1024; tr = t >> 5; tc = t & 31;
    } else if (bx < 1536) {            // W2: 2 x (1024x256)
        int idx = bx - 1024, mat = idx >> 8, t = idx & 255;
        src = W2 + (long)mat * 262144; dst = w2t + (long)mat * 262144;
        Kd = 1024; Nd = 256; tr = t >> 3; tc = t & 7;
    } else {                           // Wout: 256x512
        int t = bx - 1536;
        src = Wout; dst = woutt; Kd = 256; Nd = 512; tr = t >> 4; tc = t & 15;
    }
    int kr = tid >> 3, nc4 = (tid & 7) * 4;
    float4_t v = *(const float4_t*)&src[(long)(tr * 32 + kr) * Nd + tc * 32 + nc4];
    for (int j = 0; j < 4; ++j) tile[kr][nc4 + j] = v[j];
    __syncthreads();
    int nr = tid >> 3, kc4 = (tid & 7) * 4;
    unsigned short tmp[4];
    for (int j = 0; j < 4; ++j) tmp[j] = f2bf_bits(tile[kc4 + j][nr]);
    uint2 uu;
    uu.x = (unsigned)tmp[0] | ((unsigned)tmp[1] << 16);
    uu.y = (unsigned)tmp[2] | ((unsigned)tmp[3] << 16);
    *(uint2*)&dst[(long)(tc * 32 + nr) * Kd + tr * 32 + kc4] = uu;
}

// ---------------------------------------------------------------------------
// Token embedding gather + rank-2 delta projection
// ---------------------------------------------------------------------------
__global__ __launch_bounds__(256) void embed_kernel(
    const int* __restrict__ tokens, const float* __restrict__ emb,
    const float* __restrict__ w_in, const float* __restrict__ w_out,
    float* __restrict__ x, float* __restrict__ delta)
{
    int bt = blockIdx.x;
    int d  = threadIdx.x;
    int tok = tokens[bt];
    float e = emb[tok * D_ + d];
    x[(long)bt * D_ + d] = e;

    __shared__ float r0s[256], r1s[256];
    r0s[d] = e * w_in[d * 2 + 0];
    r1s[d] = e * w_in[d * 2 + 1];
    __syncthreads();
    for (int off = 128; off > 0; off >>= 1) {
        if (d < off) { r0s[d] += r0s[d + off]; r1s[d] += r1s[d + off]; }
        __syncthreads();
    }
    float r0 = r0s[0], r1 = r1s[0];
    if (d < H_ * NB_) {
        delta[(long)bt * (H_ * NB_) + d] =
            r0 * w_out[d] + r1 * w_out[H_ * NB_ + d];
    }
}

// ---------------------------------------------------------------------------
// cumsum over T per (b, channel) + cos/sin
// ---------------------------------------------------------------------------
__global__ __launch_bounds__(256) void cumsum_kernel(
    const float* __restrict__ delta, const float* __restrict__ omega,
    float* __restrict__ cosb, float* __restrict__ sinb)
{
    int c = blockIdx.x & (H_ * NB_ - 1);
    int b = blockIdx.x >> 7;
    int tid = threadIdx.x;
    float om = omega[c];
    int h = c >> 5, nb = c & (NB_ - 1);

    float vals[8];
    float s = 0.0f;
    for (int i = 0; i < 8; ++i) {
        int t = tid * 8 + i;
        vals[i] = delta[((long)b * T_ + t) * (H_ * NB_) + c];
        s += vals[i];
    }
    __shared__ float sc[256];
    sc[tid] = s;
    __syncthreads();
    for (int off = 1; off < 256; off <<= 1) {
        float v = (tid >= off) ? sc[tid - off] : 0.0f;
        __syncthreads();
        sc[tid] += v;
        __syncthreads();
    }
    float run = sc[tid] - s;
    for (int i = 0; i < 8; ++i) {
        run += vals[i];
        float ang = run * om;
        int t = tid * 8 + i;
        long oi = ((long)(b * H_ + h) * T_ + t) * NB_ + nb;
        cosb[oi] = cosf(ang);
        sinb[oi] = sinf(ang);
    }
}

// ---------------------------------------------------------------------------
// LayerNorm (fp32 in) -> bf16 out
// ---------------------------------------------------------------------------
__global__ __launch_bounds__(256) void ln_kernel(
    const float* __restrict__ x, const float* __restrict__ g,
    const float* __restrict__ b, unsigned short* __restrict__ out)
{
    int row = blockIdx.x;
    int d = threadIdx.x;
    float v = x[(long)row * D_ + d];
    __shared__ float ss[256], sq[256];
    ss[d] = v; sq[d] = v * v;
    __syncthreads();
    for (int off = 128; off > 0; off >>= 1) {
        if (d < off) { ss[d] += ss[d + off]; sq[d] += sq[d + off]; }
        __syncthreads();
    }
    float mu  = ss[0] * (1.0f / D_);
    float var = sq[0] * (1.0f / D_) - mu * mu;
    float inv = rsqrtf(var + 1e-5f);
    out[(long)row * D_ + d] = f2bf_bits((v - mu) * inv * g[d] + b[d]);
}

// ---------------------------------------------------------------------------
// MFMA GEMM: C[M,N] = A[M,K](bf16) @ Bt[N,K](bf16)^T + bias.
// 64x64 tile, BK=64, 4 waves x (16x64 strip), 16x16x32 MFMA.
// mode 0: fp32 out, row-major, bias per col, optional res add + gelu
// mode 1: bf16 out, row-major, bias per col, optional gelu
// mode 2: bf16 out, row-major, bias per ROW (for V^T via swapped operands)
// mode 3: bf16 out in (B,H,T,DH) layout with RoPE applied + qscale folded
// ---------------------------------------------------------------------------
__global__ __launch_bounds__(256) void gemm_mfma(
    const unsigned short* __restrict__ A, const unsigned short* __restrict__ Bt,
    const float* __restrict__ bias, const float* __restrict__ res,
    float* __restrict__ outf, unsigned short* __restrict__ outb,
    const float* __restrict__ ropeC, const float* __restrict__ ropeS,
    float qscale, int M, int N, int K, int mode, int do_gelu)
{
    __shared__ __align__(16) short As[64 * 72];
    __shared__ __align__(16) short Bs[64 * 72];
    int tid = threadIdx.x;
    int w = tid >> 6, lane = tid & 63, quad = lane >> 4, l16 = lane & 15;
    int n0 = blockIdx.x * 64, r0 = blockIdx.y * 64;

    float4_t acc[4];
    for (int nt = 0; nt < 4; ++nt) acc[nt] = (float4_t){0.f, 0.f, 0.f, 0.f};

    for (int k0 = 0; k0 < K; k0 += 64) {
        __syncthreads();
        for (int i = 0; i < 2; ++i) {
            int e = tid + 256 * i;
            int r = e >> 3, c8 = e & 7;
            *(short8_t*)&As[r * 72 + c8 * 8] =
                *(const short8_t*)&A[(long)(r0 + r) * K + k0 + c8 * 8];
            *(short8_t*)&Bs[r * 72 + c8 * 8] =
                *(const short8_t*)&Bt[(long)(n0 + r) * K + k0 + c8 * 8];
        }
        __syncthreads();
        for (int kq = 0; kq < 2; ++kq) {
            short8_t a = *(const short8_t*)&As[(w * 16 + l16) * 72 + kq * 32 + quad * 8];
            for (int nt = 0; nt < 4; ++nt) {
                short8_t bfr = *(const short8_t*)&Bs[(nt * 16 + l16) * 72 + kq * 32 + quad * 8];
                acc[nt] = MFMA16(a, bfr, acc[nt]);
            }
        }
    }

    int h_head = n0 >> 6;   // valid for mode 3 (N==256, tiles are head-aligned)
    for (int nt = 0; nt < 4; ++nt) {
        int n = n0 + nt * 16 + l16;
        float bcol = (mode == 2) ? 0.0f : bias[n];
        for (int r = 0; r < 4; ++r) {
            int row = r0 + w * 16 + quad * 4 + r;
            float v = acc[nt][r] + ((mode == 2) ? bias[row] : bcol);
            if (res) v += res[(long)row * N + n];
            if (do_gelu) v = 0.5f * v * (1.0f + erff(v * 0.70710678118654752f));
            if (mode == 0) {
                outf[(long)row * N + n] = v;
            } else if (mode == 1 || mode == 2) {
                outb[(long)row * N + n] = f2bf_bits(v);
            } else {  // mode 3: rope (pairs are adjacent columns -> lane^1)
                float vp = __shfl_xor(v, 1);
                int bb = row >> 11, t = row & (T_ - 1);
                int nb = (n & 63) >> 1;
                long ci = ((long)(bb * H_ + h_head) * T_ + t) * NB_ + nb;
                float c = ropeC[ci], sn = ropeS[ci];
                float ov = (l16 & 1) ? (vp * sn + v * c) : (v * c - vp * sn);
                outb[((long)(bb * H_ + h_head) * T_ + t) * DH_ + (n & 63)] =
                    f2bf_bits(ov * qscale);
            }
        }
    }
}

// ---------------------------------------------------------------------------
// Flash-attention inner segment (swapped QK^T layout, r4-verified numerics).
// Processes k-tiles [kt0, ktEnd] for one 64-row q-tile (4 waves, 16 rows/wave).
// State (m, l, o-unnormalized) carried by reference.
// ---------------------------------------------------------------------------
__device__ __forceinline__ void flash_seg(
    float& m_r, float& l_r, float4_t o[4], const short8_t aq[2],
    const unsigned short* __restrict__ kb_base,
    const unsigned short* __restrict__ vt_base,
    short* __restrict__ PsW,
    int kt0, int ktEnd, int qglob, int quad, int l16, bool doMask)
{
    // prefetch K fragments for first tile
    short8_t kf[4][2];
    for (int nt = 0; nt < 4; ++nt) {
        const unsigned short* kp =
            kb_base + (long)(kt0 * 64 + nt * 16 + l16) * DH_;
        kf[nt][0] = *(const short8_t*)kp;
        kf[nt][1] = *(const short8_t*)(kp + 32);
    }

    for (int kt = kt0; kt <= ktEnd; ++kt) {
        int k0 = kt * 64;

        // V fragments: issue early, consume after softmax
        short8_t vb[4][2];
        for (int nt = 0; nt < 4; ++nt)
            for (int kq = 0; kq < 2; ++kq)
                vb[nt][kq] = *(const short8_t*)(
                    vt_base + (long)(nt * 16 + l16) * (B_ * T_) + k0 + kq * 32);

        // S^T = K Q^T: lane holds S[k = nt*16+quad*4+r][q = l16]
        float4_t st[4];
        for (int nt = 0; nt < 4; ++nt) {
            float4_t sa = (float4_t){0.f, 0.f, 0.f, 0.f};
            sa = MFMA16(kf[nt][0], aq[0], sa);
            sa = MFMA16(kf[nt][1], aq[1], sa);
            st[nt] = sa;
        }

        // prefetch K for kt+1 (hidden under softmax)
        if (kt < ktEnd) {
            for (int nt = 0; nt < 4; ++nt) {
                const unsigned short* kp =
                    kb_base + (long)(k0 + 64 + nt * 16 + l16) * DH_;
                kf[nt][0] = *(const short8_t*)kp;
                kf[nt][1] = *(const short8_t*)(kp + 32);
            }
        }

        // causal mask (last tile only, if doMask) + in-lane max
        bool diag = doMask && (kt == ktEnd);
        float mt = -3.0e38f;
        for (int nt = 0; nt < 4; ++nt) {
            for (int r = 0; r < 4; ++r) {
                float sv = st[nt][r];
                if (diag && (k0 + nt * 16 + quad * 4 + r) > qglob) sv = -3.0e38f;
                st[nt][r] = sv;
                mt = fmaxf(mt, sv);
            }
        }
        mt = fmaxf(mt, __shfl_xor(mt, 16));
        mt = fmaxf(mt, __shfl_xor(mt, 32));

        float mn = fmaxf(m_r, mt);
        float alpha = __expf(m_r - mn);
        m_r = mn;

        float ac[4];
        for (int r = 0; r < 4; ++r) ac[r] = __shfl(alpha, quad * 4 + r);

        float lt = 0.0f;
        for (int nt = 0; nt < 4; ++nt) {
            for (int r = 0; r < 4; ++r) {
                float pv = __expf(st[nt][r] - m_r);
                lt += pv;
                PsW[l16 * 72 + nt * 16 + quad * 4 + r] = (short)f2bf_bits(pv);
            }
        }
        lt += __shfl_xor(lt, 16);
        lt += __shfl_xor(lt, 32);
        l_r = l_r * alpha + lt;

        for (int nt = 0; nt < 4; ++nt)
            for (int r = 0; r < 4; ++r) o[nt][r] *= ac[r];

        // O += P @ V
        for (int kq = 0; kq < 2; ++kq) {
            short8_t pa = *(const short8_t*)&PsW[l16 * 72 + kq * 32 + quad * 8];
            for (int nt = 0; nt < 4; ++nt)
                o[nt] = MFMA16(pa, vb[nt][kq], o[nt]);
        }
    }
}

// ---------------------------------------------------------------------------
// MFMA flash attention with UNIFORM-DURATION pairing + in-block k-split.
// Block = 8 waves, pair (p, 31-p). Group A (waves 0-3):
//   tile p, kt 0..p (masked)           = p+1 iters
//   tile 31-p, kt 0..15-p (unmasked)   = 16-p iters   -> 17 total, all p
// Group B (waves 4-7):
//   tile 31-p, kt 16-p..31-p (masked)  = 16 total, all p
// Every SIMD hosts one A-wave + one B-wave for the whole kernel; every
// block has identical duration. A's tile-31-p partial (o,m,l) merged with
// B's via LDS + one barrier; B writes the merged output.
// ---------------------------------------------------------------------------
__global__ __launch_bounds__(512) void attn_mfma(
    const unsigned short* __restrict__ Qb, const unsigned short* __restrict__ Kb,
    const unsigned short* __restrict__ Vt, unsigned short* __restrict__ O)
{
    __shared__ __align__(16) short Ps[8][16 * 72];
    __shared__ __align__(16) float Om[4][16 * 66];   // A's partial o (pad 66)
    __shared__ float Ml[4][16][2];                   // A's per-row m, l

    int tid = threadIdx.x;
    int w = tid >> 6, lane = tid & 63;
    int quad = lane >> 4, l16 = lane & 15;
    int bh = blockIdx.x & 15;
    int p  = blockIdx.x >> 4;            // 0..15
    int wr = w & 3;
    bool isA = (w < 4);
    int b = bh >> 2, h = bh & 3;
    int qtQ = 31 - p;                    // shared tile

    const unsigned short* kb_base = Kb + (long)bh * T_ * DH_ + quad * 8;
    const unsigned short* vt_base =
        Vt + (long)h * DH_ * (B_ * T_) + (long)b * T_ + quad * 8;
    short* PsW = &Ps[w][0];

    float m_r = -3.0e38f, l_r = 0.0f;
    float4_t o[4];
    for (int nt = 0; nt < 4; ++nt) o[nt] = (float4_t){0.f, 0.f, 0.f, 0.f};
    short8_t aq[2];

    if (isA) {
        // ---- segment 1: own tile p (full causal range) ----
        int q0 = p * 64;
        int qglob = q0 + wr * 16 + l16;
        const unsigned short* qp =
            Qb + ((long)bh * T_ + q0 + wr * 16 + l16) * DH_ + quad * 8;
        aq[0] = *(const short8_t*)qp;
        aq[1] = *(const short8_t*)(qp + 32);
        flash_seg(m_r, l_r, o, aq, kb_base, vt_base, PsW,
                  0, p, qglob, quad, l16, true);

        float linv[4];
        for (int r = 0; r < 4; ++r) linv[r] = __shfl(l_r, quad * 4 + r);
        for (int r = 0; r < 4; ++r) {
            float inv = 1.0f / linv[r];
            int trow = q0 + wr * 16 + quad * 4 + r;
            long orow = ((long)b * T_ + trow) * D_ + h * 64;
            for (int nt = 0; nt < 4; ++nt)
                O[orow + nt * 16 + l16] = f2bf_bits(o[nt][r] * inv);
        }

        // ---- segment 2: shared tile 31-p, kt 0..15-p (never masked) ----
        q0 = qtQ * 64;
        qp = Qb + ((long)bh * T_ + q0 + wr * 16 + l16) * DH_ + quad * 8;
        aq[0] = *(const short8_t*)qp;
        aq[1] = *(const short8_t*)(qp + 32);
        m_r = -3.0e38f; l_r = 0.0f;
        for (int nt = 0; nt < 4; ++nt) o[nt] = (float4_t){0.f, 0.f, 0.f, 0.f};
        flash_seg(m_r, l_r, o, aq, kb_base, vt_base, PsW,
                  0, 15 - p, 0, quad, l16, false);

        // stash partial in LDS
        for (int nt = 0; nt < 4; ++nt)
            for (int r = 0; r < 4; ++r)
                Om[wr][(quad * 4 + r) * 66 + nt * 16 + l16] = o[nt][r];
        if (quad == 0) { Ml[wr][l16][0] = m_r; Ml[wr][l16][1] = l_r; }
    } else {
        // ---- group B: shared tile 31-p, kt 16-p..31-p (masked last) ----
        int q0 = qtQ * 64;
        int qglob = q0 + wr * 16 + l16;
        const unsigned short* qp =
            Qb + ((long)bh * T_ + q0 + wr * 16 + l16) * DH_ + quad * 8;
        aq[0] = *(const short8_t*)qp;
        aq[1] = *(const short8_t*)(qp + 32);
        flash_seg(m_r, l_r, o, aq, kb_base, vt_base, PsW,
                  16 - p, 31 - p, qglob, quad, l16, true);
    }

    __syncthreads();

    if (!isA) {
        // merge A's partial with B's state, write shared-tile output
        int q0 = qtQ * 64;
        for (int r = 0; r < 4; ++r) {
            int row = quad * 4 + r;
            float mA = Ml[wr][row][0], lA = Ml[wr][row][1];
            float mB = __shfl(m_r, row);
            float lB = __shfl(l_r, row);
            float M  = fmaxf(mA, mB);
            float eA = __expf(mA - M), eB = __expf(mB - M);
            float inv = 1.0f / (lA * eA + lB * eB);
            int trow = q0 + wr * 16 + row;
            long orow = ((long)b * T_ + trow) * D_ + h * 64;
            for (int nt = 0; nt < 4; ++nt) {
                float vm = Om[wr][row * 66 + nt * 16 + l16] * eA + o[nt][r] * eB;
                O[orow + nt * 16 + l16] = f2bf_bits(vm * inv);
            }
        }
    }
}

// ---------------------------------------------------------------------------
extern "C" void kernel_launch(void* const* d_in, const int* in_sizes, int n_in,
                              void* d_out, int out_size, void* d_ws, size_t ws_size,
                              hipStream_t stream)
{
    const int*   tokens    = (const int*)d_in[0];
    const float* token_emb = (const float*)d_in[1];
    const float* w_in      = (const float*)d_in[2];
    const float* w_out     = (const float*)d_in[3];
    const float* omega     = (const float*)d_in[4];
    const float* Wq        = (const float*)d_in[5];
    const float* bq        = (const float*)d_in[6];
    const float* Wk        = (const float*)d_in[7];
    const float* bk        = (const float*)d_in[8];
    const float* Wv        = (const float*)d_in[9];
    const float* bv        = (const float*)d_in[10];
    const float* Wo        = (const float*)d_in[11];
    const float* bo        = (const float*)d_in[12];
    const float* ln1_g     = (const float*)d_in[13];
    const float* ln1_b     = (const float*)d_in[14];
    const float* ln2_g     = (const float*)d_in[15];
    const float* ln2_b     = (const float*)d_in[16];
    const float* W1        = (const float*)d_in[17];
    const float* b1        = (const float*)d_in[18];
    const float* W2        = (const float*)d_in[19];
    const float* b2        = (const float*)d_in[20];
    const float* out_g     = (const float*)d_in[21];
    const float* out_b     = (const float*)d_in[22];
    const float* Wout      = (const float*)d_in[23];
    const float* bout      = (const float*)d_in[24];

    const long NTOK = (long)B_ * T_;  // 8192
    float* xbuf = (float*)d_ws;                       // fp32 residual stream 8MB
    float* cosb = xbuf + NTOK * D_;                   // (B,H,T,NB) fp32 4MB
    float* sinb = cosb + NTOK * H_ * NB_;             // 4MB
    float* dbuf = sinb + NTOK * H_ * NB_;             // (B,T,H*NB) fp32 4MB
    unsigned short* hbuf  = (unsigned short*)(dbuf + NTOK * H_ * NB_); // bf16 LN out 4MB
    unsigned short* obuf  = hbuf + NTOK * D_;         // bf16 attn out 4MB
    unsigned short* ffbuf = obuf + NTOK * D_;         // bf16 FFN mid 16MB
    unsigned short* qb16  = ffbuf + NTOK * DFF_;      // bf16 Q (B,H,T,DH) 4MB
    unsigned short* kb16  = qb16 + NTOK * D_;         // bf16 K (B,H,T,DH) 4MB
    unsigned short* vtb   = kb16 + NTOK * D_;         // bf16 V^T [H*DH][B*T] 4MB
    unsigned short* wqt   = vtb + NTOK * D_;          // transposed bf16 weights
    unsigned short* wkt   = wqt + 2 * 65536;
    unsigned short* wvt   = wkt + 2 * 65536;
    unsigned short* wot   = wvt + 2 * 65536;
    unsigned short* w1t   = wot + 2 * 65536;
    unsigned short* w2t   = w1t + 2 * 262144;
    unsigned short* woutt = w2t + 2 * 262144;
    // total ~60 MB

    wt_kernel<<<1664, 256, 0, stream>>>(Wq, Wk, Wv, Wo, W1, W2, Wout,
                                        wqt, wkt, wvt, wot, w1t, w2t, woutt);
    embed_kernel<<<NTOK, 256, 0, stream>>>(tokens, token_emb, w_in, w_out, xbuf, dbuf);
    cumsum_kernel<<<B_ * H_ * NB_, 256, 0, stream>>>(dbuf, omega, cosb, sinb);

    for (int l = 0; l < NL_; ++l) {
        ln_kernel<<<NTOK, 256, 0, stream>>>(xbuf, ln1_g + l * D_, ln1_b + l * D_, hbuf);
        // Q: rope + 1/8 scale folded, bf16 attn layout
        gemm_mfma<<<dim3(4, 128), 256, 0, stream>>>(
            hbuf, wqt + (long)l * 65536, bq + l * D_, nullptr, nullptr, qb16,
            cosb, sinb, 0.125f, (int)NTOK, D_, D_, 3, 0);
        // K: rope folded, bf16 attn layout
        gemm_mfma<<<dim3(4, 128), 256, 0, stream>>>(
            hbuf, wkt + (long)l * 65536, bk + l * D_, nullptr, nullptr, kb16,
            cosb, sinb, 1.0f, (int)NTOK, D_, D_, 3, 0);
        // V^T via swapped operands: C[d][token] = sum_k Wv[k][d] h[token][k]
        gemm_mfma<<<dim3(128, 4), 256, 0, stream>>>(
            wvt + (long)l * 65536, hbuf, bv + l * D_, nullptr, nullptr, vtb,
            nullptr, nullptr, 0.f, D_, (int)NTOK, D_, 2, 0);
        attn_mfma<<<256, 512, 0, stream>>>(qb16, kb16, vtb, obuf);
        gemm_mfma<<<dim3(4, 128), 256, 0, stream>>>(
            obuf, wot + (long)l * 65536, bo + l * D_, xbuf, xbuf, nullptr,
            nullptr, nullptr, 0.f, (int)NTOK, D_, D_, 0, 0);
        ln_kernel<<<NTOK, 256, 0, stream>>>(xbuf, ln2_g + l * D_, ln2_b + l * D_, hbuf);
        gemm_mfma<<<dim3(16, 128), 256, 0, stream>>>(
            hbuf, w1t + (long)l * 262144, b1 + l * DFF_, nullptr, nullptr, ffbuf,
            nullptr, nullptr, 0.f, (int)NTOK, DFF_, D_, 1, 1);
        gemm_mfma<<<dim3(4, 128), 256, 0, stream>>>(
            ffbuf, w2t + (long)l * 262144, b2 + l * D_, xbuf, xbuf, nullptr,
            nullptr, nullptr, 0.f, (int)NTOK, D_, DFF_, 0, 0);
    }

    ln_kernel<<<NTOK, 256, 0, stream>>>(xbuf, out_g, out_b, hbuf);
    gemm_mfma<<<dim3(8, 128), 256, 0, stream>>>(
        hbuf, woutt, bout, nullptr, (float*)d_out, nullptr,
        nullptr, nullptr, 0.f, (int)NTOK, V_, D_, 0, 0);
}

// Round 6
// 438.242 us; speedup vs baseline: 1.3299x; 1.1843x over previous
//
#include <hip/hip_runtime.h>
#include <hip/hip_bf16.h>
#include <math.h>

#define B_   4
#define T_   2048
#define V_   512
#define D_   256
#define H_   4
#define DH_  64
#define NB_  32
#define DFF_ 1024
#define NL_  2

typedef __attribute__((ext_vector_type(8))) short short8_t;
typedef __attribute__((ext_vector_type(4))) float float4_t;

#define MFMA16(a,b,c) __builtin_amdgcn_mfma_f32_16x16x32_bf16(a,b,c,0,0,0)

__device__ __forceinline__ unsigned short f2bf_bits(float f) {
    unsigned u = __float_as_uint(f);
    u += 0x7fffu + ((u >> 16) & 1u);
    return (unsigned short)(u >> 16);
}

// ---------------------------------------------------------------------------
// Weight transpose+cast: W[K][N] fp32 -> Wt[N][K] bf16. One 32x32 tile/block.
// ---------------------------------------------------------------------------
__global__ __launch_bounds__(256) void wt_kernel(
    const float* __restrict__ Wq, const float* __restrict__ Wk,
    const float* __restrict__ Wv, const float* __restrict__ Wo,
    const float* __restrict__ W1, const float* __restrict__ W2,
    const float* __restrict__ Wout,
    unsigned short* __restrict__ wqt, unsigned short* __restrict__ wkt,
    unsigned short* __restrict__ wvt, unsigned short* __restrict__ wot,
    unsigned short* __restrict__ w1t, unsigned short* __restrict__ w2t,
    unsigned short* __restrict__ woutt)
{
    __shared__ float tile[32][33];
    int bx = blockIdx.x, tid = threadIdx.x;
    const float* src; unsigned short* dst; int Kd, Nd, tr, tc;
    if (bx < 512) {                    // Wq/Wk/Wv/Wo, 2 layers each, 256x256
        int am = bx >> 6, t = bx & 63;
        const float* s4[4] = {Wq, Wk, Wv, Wo};
        unsigned short* d4[4] = {wqt, wkt, wvt, wot};
        src = s4[am >> 1] + (long)(am & 1) * 65536;
        dst = d4[am >> 1] + (long)(am & 1) * 65536;
        Kd = 256; Nd = 256; tr = t >> 3; tc = t & 7;
    } else if (bx < 1024) {            // W1: 2 x (256x1024)
        int idx = bx - 512, mat = idx >> 8, t = idx & 255;
        src = W1 + (long)mat * 262144; dst = w1t + (long)mat * 262144;
        Kd = 256; Nd = 1024; tr = t >> 5; tc = t & 31;
    } else if (bx < 1536) {            // W2: 2 x (1024x256)
        int idx = bx - 1024, mat = idx >> 8, t = idx & 255;
        src = W2 + (long)mat * 262144; dst = w2t + (long)mat * 262144;
        Kd = 1024; Nd = 256; tr = t >> 3; tc = t & 7;
    } else {                           // Wout: 256x512
        int t = bx - 1536;
        src = Wout; dst = woutt; Kd = 256; Nd = 512; tr = t >> 4; tc = t & 15;
    }
    int kr = tid >> 3, nc4 = (tid & 7) * 4;
    float4_t v = *(const float4_t*)&src[(long)(tr * 32 + kr) * Nd + tc * 32 + nc4];
    for (int j = 0; j < 4; ++j) tile[kr][nc4 + j] = v[j];
    __syncthreads();
    int nr = tid >> 3, kc4 = (tid & 7) * 4;
    unsigned short tmp[4];
    for (int j = 0; j < 4; ++j) tmp[j] = f2bf_bits(tile[kc4 + j][nr]);
    uint2 uu;
    uu.x = (unsigned)tmp[0] | ((unsigned)tmp[1] << 16);
    uu.y = (unsigned)tmp[2] | ((unsigned)tmp[3] << 16);
    *(uint2*)&dst[(long)(tc * 32 + nr) * Kd + tr * 32 + kc4] = uu;
}

// ---------------------------------------------------------------------------
// Token embedding gather + rank-2 delta projection
// ---------------------------------------------------------------------------
__global__ __launch_bounds__(256) void embed_kernel(
    const int* __restrict__ tokens, const float* __restrict__ emb,
    const float* __restrict__ w_in, const float* __restrict__ w_out,
    float* __restrict__ x, float* __restrict__ delta)
{
    int bt = blockIdx.x;
    int d  = threadIdx.x;
    int tok = tokens[bt];
    float e = emb[tok * D_ + d];
    x[(long)bt * D_ + d] = e;

    __shared__ float r0s[256], r1s[256];
    r0s[d] = e * w_in[d * 2 + 0];
    r1s[d] = e * w_in[d * 2 + 1];
    __syncthreads();
    for (int off = 128; off > 0; off >>= 1) {
        if (d < off) { r0s[d] += r0s[d + off]; r1s[d] += r1s[d + off]; }
        __syncthreads();
    }
    float r0 = r0s[0], r1 = r1s[0];
    if (d < H_ * NB_) {
        delta[(long)bt * (H_ * NB_) + d] =
            r0 * w_out[d] + r1 * w_out[H_ * NB_ + d];
    }
}

// ---------------------------------------------------------------------------
// cumsum over T per (b, channel) + cos/sin
// ---------------------------------------------------------------------------
__global__ __launch_bounds__(256) void cumsum_kernel(
    const float* __restrict__ delta, const float* __restrict__ omega,
    float* __restrict__ cosb, float* __restrict__ sinb)
{
    int c = blockIdx.x & (H_ * NB_ - 1);
    int b = blockIdx.x >> 7;
    int tid = threadIdx.x;
    float om = omega[c];
    int h = c >> 5, nb = c & (NB_ - 1);

    float vals[8];
    float s = 0.0f;
    for (int i = 0; i < 8; ++i) {
        int t = tid * 8 + i;
        vals[i] = delta[((long)b * T_ + t) * (H_ * NB_) + c];
        s += vals[i];
    }
    __shared__ float sc[256];
    sc[tid] = s;
    __syncthreads();
    for (int off = 1; off < 256; off <<= 1) {
        float v = (tid >= off) ? sc[tid - off] : 0.0f;
        __syncthreads();
        sc[tid] += v;
        __syncthreads();
    }
    float run = sc[tid] - s;
    for (int i = 0; i < 8; ++i) {
        run += vals[i];
        float ang = run * om;
        int t = tid * 8 + i;
        long oi = ((long)(b * H_ + h) * T_ + t) * NB_ + nb;
        cosb[oi] = cosf(ang);
        sinb[oi] = sinf(ang);
    }
}

// ---------------------------------------------------------------------------
// LayerNorm (fp32 in) -> bf16 out. Wave-per-row, no LDS, no barriers.
// Grid = NTOK/4 blocks x 4 waves.
// ---------------------------------------------------------------------------
__global__ __launch_bounds__(256) void ln_kernel(
    const float* __restrict__ x, const float* __restrict__ g,
    const float* __restrict__ b, unsigned short* __restrict__ out)
{
    int w = threadIdx.x >> 6, lane = threadIdx.x & 63;
    long row = (long)blockIdx.x * 4 + w;
    float4_t v = *(const float4_t*)&x[row * D_ + lane * 4];
    float s = v[0] + v[1] + v[2] + v[3];
    float q = v[0]*v[0] + v[1]*v[1] + v[2]*v[2] + v[3]*v[3];
    for (int off = 1; off < 64; off <<= 1) {
        s += __shfl_xor(s, off);
        q += __shfl_xor(q, off);
    }
    float mu  = s * (1.0f / D_);
    float var = q * (1.0f / D_) - mu * mu;
    float inv = rsqrtf(var + 1e-5f);
    float4_t gg = *(const float4_t*)&g[lane * 4];
    float4_t bb = *(const float4_t*)&b[lane * 4];
    unsigned short h0 = f2bf_bits((v[0] - mu) * inv * gg[0] + bb[0]);
    unsigned short h1 = f2bf_bits((v[1] - mu) * inv * gg[1] + bb[1]);
    unsigned short h2 = f2bf_bits((v[2] - mu) * inv * gg[2] + bb[2]);
    unsigned short h3 = f2bf_bits((v[3] - mu) * inv * gg[3] + bb[3]);
    uint2 uu;
    uu.x = (unsigned)h0 | ((unsigned)h1 << 16);
    uu.y = (unsigned)h2 | ((unsigned)h3 << 16);
    *(uint2*)&out[row * D_ + lane * 4] = uu;
}

// ---------------------------------------------------------------------------
// MFMA GEMM: C[M,N] = A[M,K](bf16) @ Bt[N,K](bf16)^T + bias.
// 64x64 tile, BK=64, 4 waves x (16x64 strip), 16x16x32 MFMA.
// mode 0: fp32 out, row-major, bias per col, optional res add + gelu
// mode 1: bf16 out, row-major, bias per col, optional gelu
// mode 2: bf16 out, row-major, bias per ROW (for V^T via swapped operands)
// mode 3: bf16 out in (B,H,T,DH) layout with RoPE applied + qscale folded
// ---------------------------------------------------------------------------
__global__ __launch_bounds__(256) void gemm_mfma(
    const unsigned short* __restrict__ A, const unsigned short* __restrict__ Bt,
    const float* __restrict__ bias, const float* __restrict__ res,
    float* __restrict__ outf, unsigned short* __restrict__ outb,
    const float* __restrict__ ropeC, const float* __restrict__ ropeS,
    float qscale, int M, int N, int K, int mode, int do_gelu)
{
    __shared__ __align__(16) short As[64 * 72];
    __shared__ __align__(16) short Bs[64 * 72];
    int tid = threadIdx.x;
    int w = tid >> 6, lane = tid & 63, quad = lane >> 4, l16 = lane & 15;
    int n0 = blockIdx.x * 64, r0 = blockIdx.y * 64;

    float4_t acc[4];
    for (int nt = 0; nt < 4; ++nt) acc[nt] = (float4_t){0.f, 0.f, 0.f, 0.f};

    for (int k0 = 0; k0 < K; k0 += 64) {
        __syncthreads();
        for (int i = 0; i < 2; ++i) {
            int e = tid + 256 * i;
            int r = e >> 3, c8 = e & 7;
            *(short8_t*)&As[r * 72 + c8 * 8] =
                *(const short8_t*)&A[(long)(r0 + r) * K + k0 + c8 * 8];
            *(short8_t*)&Bs[r * 72 + c8 * 8] =
                *(const short8_t*)&Bt[(long)(n0 + r) * K + k0 + c8 * 8];
        }
        __syncthreads();
        for (int kq = 0; kq < 2; ++kq) {
            short8_t a = *(const short8_t*)&As[(w * 16 + l16) * 72 + kq * 32 + quad * 8];
            for (int nt = 0; nt < 4; ++nt) {
                short8_t bfr = *(const short8_t*)&Bs[(nt * 16 + l16) * 72 + kq * 32 + quad * 8];
                acc[nt] = MFMA16(a, bfr, acc[nt]);
            }
        }
    }

    int h_head = n0 >> 6;   // valid for mode 3 (N==256, tiles are head-aligned)
    for (int nt = 0; nt < 4; ++nt) {
        int n = n0 + nt * 16 + l16;
        float bcol = (mode == 2) ? 0.0f : bias[n];
        for (int r = 0; r < 4; ++r) {
            int row = r0 + w * 16 + quad * 4 + r;
            float v = acc[nt][r] + ((mode == 2) ? bias[row] : bcol);
            if (res) v += res[(long)row * N + n];
            if (do_gelu) v = 0.5f * v * (1.0f + erff(v * 0.70710678118654752f));
            if (mode == 0) {
                outf[(long)row * N + n] = v;
            } else if (mode == 1 || mode == 2) {
                outb[(long)row * N + n] = f2bf_bits(v);
            } else {  // mode 3: rope (pairs are adjacent columns -> lane^1)
                float vp = __shfl_xor(v, 1);
                int bb = row >> 11, t = row & (T_ - 1);
                int nb = (n & 63) >> 1;
                long ci = ((long)(bb * H_ + h_head) * T_ + t) * NB_ + nb;
                float c = ropeC[ci], sn = ropeS[ci];
                float ov = (l16 & 1) ? (vp * sn + v * c) : (v * c - vp * sn);
                outb[((long)(bb * H_ + h_head) * T_ + t) * DH_ + (n & 63)] =
                    f2bf_bits(ov * qscale);
            }
        }
    }
}

// ---------------------------------------------------------------------------
// MFMA flash attention v6: LDS-SHARED K/V tiles (4x global-traffic cut).
// Block = 8 waves; group A (waves 0-3) / group B (waves 4-7); pair (p, 31-p):
//   A: tile p kt 0..p (masked last), then tile 31-p kt 0..15-p  -> 17 laps
//   B: tile 31-p kt 16-p..31-p (masked last)                    -> 16 laps + idle
// Uniform 17-lap loop, 2 barriers/lap. Per lap each group stages its next
// K-tile + V-tile (8KB+8KB) cooperatively: each wave loads 1/4 (4x16B) into
// regs before compute (latency hidden under compute), ds_writes after bar1.
// Compute reads fragments from LDS (72-short stride, 2-way-conflict-free).
// Numerics identical to r5 (swapped QK^T, per-lane softmax, Ps strip, merge).
// ---------------------------------------------------------------------------
__global__ __launch_bounds__(512) void attn_mfma(
    const unsigned short* __restrict__ Qb, const unsigned short* __restrict__ Kb,
    const unsigned short* __restrict__ Vt, unsigned short* __restrict__ O)
{
    __shared__ __align__(16) short KsS[2][64 * 72];
    __shared__ __align__(16) short VsS[2][64 * 72];
    union PsOm { short Ps[8][16 * 72]; float Om[4][16 * 66]; };
    __shared__ __align__(16) PsOm U;
    __shared__ float Ml[4][16][2];

    int tid = threadIdx.x;
    int w = tid >> 6, lane = tid & 63;
    int quad = lane >> 4, l16 = lane & 15;
    int bh = blockIdx.x & 15;
    int p  = blockIdx.x >> 4;            // 0..15
    int wr = w & 3;
    int g  = w >> 2;                     // 0 = group A, 1 = group B
    int b = bh >> 2, h = bh & 3;
    int qtS = 31 - p;                    // shared tile

    const unsigned short* kgb = Kb + (long)bh * T_ * DH_;
    const unsigned short* vgb = Vt + (long)h * DH_ * (B_ * T_) + (long)b * T_;
    short* PsW = &U.Ps[w][0];

    int row0 = wr * 16 + (lane >> 3);    // staging row (this lane, i=0)
    int c80  = (lane & 7) * 8;           // staging col offset (shorts)

    // initial Q frags
    int q0 = (g == 0 ? p : qtS) * 64;
    int qglob = q0 + wr * 16 + l16;
    const unsigned short* qp =
        Qb + ((long)bh * T_ + q0 + wr * 16 + l16) * DH_ + quad * 8;
    short8_t aq[2];
    aq[0] = *(const short8_t*)qp;
    aq[1] = *(const short8_t*)(qp + 32);

    float m_r = -3.0e38f, l_r = 0.0f;
    float4_t o[4];
    for (int nt = 0; nt < 4; ++nt) o[nt] = (float4_t){0.f, 0.f, 0.f, 0.f};

    // prologue: stage lap-0 tiles
    {
        int k0n = (g == 0) ? 0 : (16 - p) * 64;
        for (int i = 0; i < 2; ++i) {
            int row = row0 + 8 * i;
            short8_t kv = *(const short8_t*)&kgb[(long)(k0n + row) * DH_ + c80];
            short8_t vv = *(const short8_t*)&vgb[(long)row * (B_ * T_) + k0n + c80];
            *(short8_t*)&KsS[g][row * 72 + c80] = kv;
            *(short8_t*)&VsS[g][row * 72 + c80] = vv;
        }
    }
    __syncthreads();

    for (int j = 0; j < 17; ++j) {
        bool idle  = (g == 1) && (j == 16);
        bool haveN = (j < 16) && !((g == 1) && (j == 15));

        // issue next-lap global loads into registers (latency hides under compute)
        short8_t stK[2], stV[2];
        if (haveN) {
            int jn = j + 1;
            int k0n = (g == 0) ? ((jn <= p) ? jn * 64 : (jn - p - 1) * 64)
                               : (16 - p + jn) * 64;
            for (int i = 0; i < 2; ++i) {
                int row = row0 + 8 * i;
                stK[i] = *(const short8_t*)&kgb[(long)(k0n + row) * DH_ + c80];
                stV[i] = *(const short8_t*)&vgb[(long)row * (B_ * T_) + k0n + c80];
            }
        }

        if (!idle) {
            int k0 = (g == 0) ? ((j <= p) ? j * 64 : (j - p - 1) * 64)
                              : (16 - p + j) * 64;
            bool msk = (g == 0) ? (j == p) : (j == 15);

            // fragments from shared LDS tiles
            short8_t kf[4][2], vb[4][2];
            for (int nt = 0; nt < 4; ++nt) {
                const short* kb_ = &KsS[g][(nt * 16 + l16) * 72 + quad * 8];
                const short* vb_ = &VsS[g][(nt * 16 + l16) * 72 + quad * 8];
                kf[nt][0] = *(const short8_t*)kb_;
                kf[nt][1] = *(const short8_t*)(kb_ + 32);
                vb[nt][0] = *(const short8_t*)vb_;
                vb[nt][1] = *(const short8_t*)(vb_ + 32);
            }

            // S^T = K Q^T: lane holds S[k = nt*16+quad*4+r][q = l16]
            float4_t st[4];
            for (int nt = 0; nt < 4; ++nt) {
                float4_t sa = (float4_t){0.f, 0.f, 0.f, 0.f};
                sa = MFMA16(kf[nt][0], aq[0], sa);
                sa = MFMA16(kf[nt][1], aq[1], sa);
                st[nt] = sa;
            }

            // causal mask (last tile of masked segment) + in-lane max
            float mt = -3.0e38f;
            for (int nt = 0; nt < 4; ++nt) {
                for (int r = 0; r < 4; ++r) {
                    float sv = st[nt][r];
                    if (msk && (k0 + nt * 16 + quad * 4 + r) > qglob) sv = -3.0e38f;
                    st[nt][r] = sv;
                    mt = fmaxf(mt, sv);
                }
            }
            mt = fmaxf(mt, __shfl_xor(mt, 16));
            mt = fmaxf(mt, __shfl_xor(mt, 32));

            float mn = fmaxf(m_r, mt);
            float alpha = __expf(m_r - mn);
            m_r = mn;

            float ac[4];
            for (int r = 0; r < 4; ++r) ac[r] = __shfl(alpha, quad * 4 + r);

            float lt = 0.0f;
            for (int nt = 0; nt < 4; ++nt) {
                for (int r = 0; r < 4; ++r) {
                    float pv = __expf(st[nt][r] - m_r);
                    lt += pv;
                    PsW[l16 * 72 + nt * 16 + quad * 4 + r] = (short)f2bf_bits(pv);
                }
            }
            lt += __shfl_xor(lt, 16);
            lt += __shfl_xor(lt, 32);
            l_r = l_r * alpha + lt;

            for (int nt = 0; nt < 4; ++nt)
                for (int r = 0; r < 4; ++r) o[nt][r] *= ac[r];

            // O += P @ V (wave-private P strip)
            for (int kq = 0; kq < 2; ++kq) {
                short8_t pa = *(const short8_t*)&PsW[l16 * 72 + kq * 32 + quad * 8];
                for (int nt = 0; nt < 4; ++nt)
                    o[nt] = MFMA16(pa, vb[nt][kq], o[nt]);
            }

            // A-group transition: finalize tile p, switch to shared tile
            if (g == 0 && j == p) {
                float linv[4];
                for (int r = 0; r < 4; ++r) linv[r] = __shfl(l_r, quad * 4 + r);
                for (int r = 0; r < 4; ++r) {
                    float inv = 1.0f / linv[r];
                    int trow = p * 64 + wr * 16 + quad * 4 + r;
                    long orow = ((long)b * T_ + trow) * D_ + h * 64;
                    for (int nt = 0; nt < 4; ++nt)
                        O[orow + nt * 16 + l16] = f2bf_bits(o[nt][r] * inv);
                }
                m_r = -3.0e38f; l_r = 0.0f;
                for (int nt = 0; nt < 4; ++nt) o[nt] = (float4_t){0.f, 0.f, 0.f, 0.f};
                const unsigned short* qp2 =
                    Qb + ((long)bh * T_ + qtS * 64 + wr * 16 + l16) * DH_ + quad * 8;
                aq[0] = *(const short8_t*)qp2;
                aq[1] = *(const short8_t*)(qp2 + 32);
                qglob = qtS * 64 + wr * 16 + l16;   // unused (no mask in seg 2)
            }
        }

        if (j < 16) {
            __syncthreads();                 // all reads of current tiles done
            if (haveN) {
                for (int i = 0; i < 2; ++i) {
                    int row = row0 + 8 * i;
                    *(short8_t*)&KsS[g][row * 72 + c80] = stK[i];
                    *(short8_t*)&VsS[g][row * 72 + c80] = stV[i];
                }
            }
            __syncthreads();                 // next tiles visible
        }
    }

    __syncthreads();                         // lap-16 Ps reads done before stash
    if (g == 0) {
        for (int nt = 0; nt < 4; ++nt)
            for (int r = 0; r < 4; ++r)
                U.Om[wr][(quad * 4 + r) * 66 + nt * 16 + l16] = o[nt][r];
        if (quad == 0) { Ml[wr][l16][0] = m_r; Ml[wr][l16][1] = l_r; }
    }
    __syncthreads();
    if (g == 1) {
        int q0s = qtS * 64;
        for (int r = 0; r < 4; ++r) {
            int row = quad * 4 + r;
            float mA = Ml[wr][row][0], lA = Ml[wr][row][1];
            float mB = __shfl(m_r, row);
            float lB = __shfl(l_r, row);
            float M  = fmaxf(mA, mB);
            float eA = __expf(mA - M), eB = __expf(mB - M);
            float inv = 1.0f / (lA * eA + lB * eB);
            int trow = q0s + wr * 16 + row;
            long orow = ((long)b * T_ + trow) * D_ + h * 64;
            for (int nt = 0; nt < 4; ++nt) {
                float vm = U.Om[wr][row * 66 + nt * 16 + l16] * eA + o[nt][r] * eB;
                O[orow + nt * 16 + l16] = f2bf_bits(vm * inv);
            }
        }
    }
}

// ---------------------------------------------------------------------------
extern "C" void kernel_launch(void* const* d_in, const int* in_sizes, int n_in,
                              void* d_out, int out_size, void* d_ws, size_t ws_size,
                              hipStream_t stream)
{
    const int*   tokens    = (const int*)d_in[0];
    const float* token_emb = (const float*)d_in[1];
    const float* w_in      = (const float*)d_in[2];
    const float* w_out     = (const float*)d_in[3];
    const float* omega     = (const float*)d_in[4];
    const float* Wq        = (const float*)d_in[5];
    const float* bq        = (const float*)d_in[6];
    const float* Wk        = (const float*)d_in[7];
    const float* bk        = (const float*)d_in[8];
    const float* Wv        = (const float*)d_in[9];
    const float* bv        = (const float*)d_in[10];
    const float* Wo        = (const float*)d_in[11];
    const float* bo        = (const float*)d_in[12];
    const float* ln1_g     = (const float*)d_in[13];
    const float* ln1_b     = (const float*)d_in[14];
    const float* ln2_g     = (const float*)d_in[15];
    const float* ln2_b     = (const float*)d_in[16];
    const float* W1        = (const float*)d_in[17];
    const float* b1        = (const float*)d_in[18];
    const float* W2        = (const float*)d_in[19];
    const float* b2        = (const float*)d_in[20];
    const float* out_g     = (const float*)d_in[21];
    const float* out_b     = (const float*)d_in[22];
    const float* Wout      = (const float*)d_in[23];
    const float* bout      = (const float*)d_in[24];

    const long NTOK = (long)B_ * T_;  // 8192
    float* xbuf = (float*)d_ws;                       // fp32 residual stream 8MB
    float* cosb = xbuf + NTOK * D_;                   // (B,H,T,NB) fp32 4MB
    float* sinb = cosb + NTOK * H_ * NB_;             // 4MB
    float* dbuf = sinb + NTOK * H_ * NB_;             // (B,T,H*NB) fp32 4MB
    unsigned short* hbuf  = (unsigned short*)(dbuf + NTOK * H_ * NB_); // bf16 LN out 4MB
    unsigned short* obuf  = hbuf + NTOK * D_;         // bf16 attn out 4MB
    unsigned short* ffbuf = obuf + NTOK * D_;         // bf16 FFN mid 16MB
    unsigned short* qb16  = ffbuf + NTOK * DFF_;      // bf16 Q (B,H,T,DH) 4MB
    unsigned short* kb16  = qb16 + NTOK * D_;         // bf16 K (B,H,T,DH) 4MB
    unsigned short* vtb   = kb16 + NTOK * D_;         // bf16 V^T [H*DH][B*T] 4MB
    unsigned short* wqt   = vtb + NTOK * D_;          // transposed bf16 weights
    unsigned short* wkt   = wqt + 2 * 65536;
    unsigned short* wvt   = wkt + 2 * 65536;
    unsigned short* wot   = wvt + 2 * 65536;
    unsigned short* w1t   = wot + 2 * 65536;
    unsigned short* w2t   = w1t + 2 * 262144;
    unsigned short* woutt = w2t + 2 * 262144;
    // total ~60 MB

    wt_kernel<<<1664, 256, 0, stream>>>(Wq, Wk, Wv, Wo, W1, W2, Wout,
                                        wqt, wkt, wvt, wot, w1t, w2t, woutt);
    embed_kernel<<<NTOK, 256, 0, stream>>>(tokens, token_emb, w_in, w_out, xbuf, dbuf);
    cumsum_kernel<<<B_ * H_ * NB_, 256, 0, stream>>>(dbuf, omega, cosb, sinb);

    for (int l = 0; l < NL_; ++l) {
        ln_kernel<<<2048, 256, 0, stream>>>(xbuf, ln1_g + l * D_, ln1_b + l * D_, hbuf);
        // Q: rope + 1/8 scale folded, bf16 attn layout
        gemm_mfma<<<dim3(4, 128), 256, 0, stream>>>(
            hbuf, wqt + (long)l * 65536, bq + l * D_, nullptr, nullptr, qb16,
            cosb, sinb, 0.125f, (int)NTOK, D_, D_, 3, 0);
        // K: rope folded, bf16 attn layout
        gemm_mfma<<<dim3(4, 128), 256, 0, stream>>>(
            hbuf, wkt + (long)l * 65536, bk + l * D_, nullptr, nullptr, kb16,
            cosb, sinb, 1.0f, (int)NTOK, D_, D_, 3, 0);
        // V^T via swapped operands: C[d][token] = sum_k Wv[k][d] h[token][k]
        gemm_mfma<<<dim3(128, 4), 256, 0, stream>>>(
            wvt + (long)l * 65536, hbuf, bv + l * D_, nullptr, nullptr, vtb,
            nullptr, nullptr, 0.f, D_, (int)NTOK, D_, 2, 0);
        attn_mfma<<<256, 512, 0, stream>>>(qb16, kb16, vtb, obuf);
        gemm_mfma<<<dim3(4, 128), 256, 0, stream>>>(
            obuf, wot + (long)l * 65536, bo + l * D_, xbuf, xbuf, nullptr,
            nullptr, nullptr, 0.f, (int)NTOK, D_, D_, 0, 0);
        ln_kernel<<<2048, 256, 0, stream>>>(xbuf, ln2_g + l * D_, ln2_b + l * D_, hbuf);
        gemm_mfma<<<dim3(16, 128), 256, 0, stream>>>(
            hbuf, w1t + (long)l * 262144, b1 + l * DFF_, nullptr, nullptr, ffbuf,
            nullptr, nullptr, 0.f, (int)NTOK, DFF_, D_, 1, 1);
        gemm_mfma<<<dim3(4, 128), 256, 0, stream>>>(
            ffbuf, w2t + (long)l * 262144, b2 + l * D_, xbuf, xbuf, nullptr,
            nullptr, nullptr, 0.f, (int)NTOK, D_, DFF_, 0, 0);
    }

    ln_kernel<<<2048, 256, 0, stream>>>(xbuf, out_g, out_b, hbuf);
    gemm_mfma<<<dim3(8, 128), 256, 0, stream>>>(
        hbuf, woutt, bout, nullptr, (float*)d_out, nullptr,
        nullptr, nullptr, 0.f, (int)NTOK, V_, D_, 0, 0);
}